// Round 4
// baseline (877.986 us; speedup 1.0000x reference)
//
#include <hip/hip_runtime.h>
#include <hip/hip_bf16.h>

#define N_NODES 131072
#define N_EDGES 1048576
#define HID 128
#define NB 512
#define PPG 32
#define NKEYS (4 * N_NODES)
#define NTILES (NKEYS / 256)
#define KPROJ 160              // 133 real K, zero-padded
#define KLAY  512              // 4 types x 128

typedef short bf16x8 __attribute__((ext_vector_type(8)));
typedef float f32x4  __attribute__((ext_vector_type(4)));

__device__ __forceinline__ float bf2f(unsigned short u) {
    return __uint_as_float(((unsigned int)u) << 16);
}
__device__ __forceinline__ unsigned short f2bf(float x) {
    unsigned int u = __float_as_uint(x);
    unsigned int r = ((u >> 16) & 1u) + 0x7fffu;   // RNE
    return (unsigned short)((u + r) >> 16);
}
__device__ __forceinline__ unsigned int pack2(float a, float b) {
    return (unsigned int)f2bf(a) | ((unsigned int)f2bf(b) << 16);
}

// ===========================================================================
// CSR build: key = etype*N + dst; edge payload = int2{src, norm-bits}
// ===========================================================================
__global__ void count_kernel(const int* __restrict__ dst, const int* __restrict__ etype,
                             int* __restrict__ rp) {
    int e = blockIdx.x * blockDim.x + threadIdx.x;
    if (e >= N_EDGES) return;
    atomicAdd(rp + etype[e] * N_NODES + dst[e], 1);
}

__global__ void scan_tile_kernel(int* __restrict__ rp, int* __restrict__ tsum) {
    __shared__ int s[256];
    int g = blockIdx.x * 256 + threadIdx.x;
    int v = rp[g];
    s[threadIdx.x] = v;
    __syncthreads();
    for (int off = 1; off < 256; off <<= 1) {
        int tv = (threadIdx.x >= off) ? s[threadIdx.x - off] : 0;
        __syncthreads();
        s[threadIdx.x] += tv;
        __syncthreads();
    }
    rp[g] = s[threadIdx.x] - v;
    if (threadIdx.x == 255) tsum[blockIdx.x] = s[255];
}

__global__ void scan_tsum_kernel(int* __restrict__ tsum) {
    __shared__ int s[256];
    int t = threadIdx.x;
    int loc[8]; int sum = 0;
#pragma unroll
    for (int i = 0; i < 8; ++i) { loc[i] = tsum[t * 8 + i]; sum += loc[i]; }
    s[t] = sum;
    __syncthreads();
    for (int off = 1; off < 256; off <<= 1) {
        int tv = (t >= off) ? s[t - off] : 0;
        __syncthreads();
        s[t] += tv;
        __syncthreads();
    }
    int run = s[t] - sum;
#pragma unroll
    for (int i = 0; i < 8; ++i) { int v = loc[i]; tsum[t * 8 + i] = run; run += v; }
}

__global__ void scan_add_kernel(int* __restrict__ rp, const int* __restrict__ tsum) {
    int g = blockIdx.x * 256 + threadIdx.x;
    rp[g] += tsum[g >> 8];
}

__global__ void scatter_kernel(const int* __restrict__ src, const int* __restrict__ dst,
                               const int* __restrict__ etype, const float* __restrict__ norm,
                               int* __restrict__ rp, int2* __restrict__ erec) {
    int e = blockIdx.x * blockDim.x + threadIdx.x;
    if (e >= N_EDGES) return;
    int key = etype[e] * N_NODES + dst[e];
    int pos = atomicAdd(rp + key, 1);
    erec[pos] = make_int2(src[e], __float_as_int(norm[e]));
}

// ===========================================================================
// Weight pre-transpose to bf16 [outcol][k] layout.
// ===========================================================================
__global__ void wtrans_kernel(const float* __restrict__ W_t, const float* __restrict__ W_r,
                              unsigned short* __restrict__ WTp, unsigned short* __restrict__ WTl) {
    int u = blockIdx.x * 256 + threadIdx.x;
    if (u < 2560) {                       // proj: 128 cols x 20 kgroups
        int c = u / 20, k0 = (u % 20) * 8;
#pragma unroll
        for (int j = 0; j < 8; ++j) {
            int k = k0 + j;
            float v = (k < 133) ? W_t[k * HID + c] : 0.f;
            WTp[c * KPROJ + k] = f2bf(v);
        }
    } else if (u < 2560 + 16384) {        // layers: 2 x 128 cols x 64 kgroups
        int v = u - 2560;
        int l = v / 8192; int rr = v % 8192;
        int c = rr / 64; int k0 = (rr % 64) * 8;
#pragma unroll
        for (int j = 0; j < 8; ++j) {
            int k = k0 + j; int t = k >> 7; int i = k & 127;
            float w = W_r[(((size_t)(l * 4 + t) * HID) + i) * HID + c];
            WTl[((size_t)l * HID + c) * KLAY + k] = f2bf(w);
        }
    }
}

// ===========================================================================
// prep: build A0[N][160] bf16 = concat(emb', feats, zeros).  wave per node.
// ===========================================================================
__global__ __launch_bounds__(256) void prep_kernel(
        const int* __restrict__ rp, const int2* __restrict__ erec,
        const int* __restrict__ gid,
        const int* __restrict__ spo, const int* __restrict__ access,
        const int* __restrict__ pre, const float* __restrict__ emb,
        unsigned short* __restrict__ A0) {
    int wave = threadIdx.x >> 6, lane = threadIdx.x & 63;
    int n = blockIdx.x * 4 + wave;
    int s0 = spo[n * 3], s1 = spo[n * 3 + 1], s2 = spo[n * 3 + 2];
    int rb = n ? rp[n - 1] : 0, re = rp[n];
    float ax, ay;
    if ((s0 + s2) > 0 && re > rb) {
        ax = 0.f; ay = 0.f;
        for (int i = rb; i < re; ++i) {
            int2 er = erec[i];
            float nm = __int_as_float(er.y);
            float2 v = ((const float2*)(emb + (size_t)gid[er.x] * HID))[lane];
            ax += v.x * nm; ay += v.y * nm;
        }
    } else {
        float2 v = ((const float2*)(emb + (size_t)gid[n] * HID))[lane];
        ax = v.x; ay = v.y;
    }
    unsigned int* row = (unsigned int*)(A0 + (size_t)n * KPROJ);
    row[lane] = pack2(ax, ay);
    if (lane < 16) {
        int c0 = 128 + lane * 2;
        float f0 = 0.f, f1 = 0.f;
        if (c0 == 128)      { f0 = (float)s0;      f1 = (float)s1; }
        else if (c0 == 130) { f0 = (float)s2;      f1 = (float)access[n]; }
        else if (c0 == 132) { f0 = (float)pre[n];  f1 = 0.f; }
        row[64 + lane] = pack2(f0, f1);
    }
}

// ===========================================================================
// proj MFMA GEMM (K=KPROJ): hb = A0 @ WTp^T + b_t
// ===========================================================================
__global__ __launch_bounds__(256) void gemm_kernel(
        const unsigned short* __restrict__ A, int K,
        const unsigned short* __restrict__ WT, const float* __restrict__ bias,
        unsigned short* __restrict__ hb) {
    __shared__ unsigned short At[128][136];
    __shared__ unsigned short Bt[128][136];
    int tid = threadIdx.x;
    int base = blockIdx.x * 128;
    int wid = tid >> 6, lane = tid & 63;
    int wr = wid >> 1, wc = wid & 1;
    int lr = lane & 15, lk = (lane >> 4) * 8;
    f32x4 acc[4][4];
#pragma unroll
    for (int m = 0; m < 4; ++m)
#pragma unroll
        for (int n = 0; n < 4; ++n) { acc[m][n][0] = 0.f; acc[m][n][1] = 0.f; acc[m][n][2] = 0.f; acc[m][n][3] = 0.f; }
    int row2 = tid >> 1, half = tid & 1;
    for (int k0 = 0; k0 < K; k0 += 128) {
        int bk = K - k0; if (bk > 128) bk = 128;
        int hw = bk >> 1;
        int nld = bk >> 4;
        const unsigned short* ga = A  + (size_t)(base + row2) * K + k0 + half * hw;
        const unsigned short* gb = WT + (size_t)row2 * K + k0 + half * hw;
        __syncthreads();
        for (int i = 0; i < nld; ++i) {
            uint4 va = ((const uint4*)ga)[i];
            *((uint4*)&At[row2][half * hw + i * 8]) = va;
            uint4 vb = ((const uint4*)gb)[i];
            *((uint4*)&Bt[row2][half * hw + i * 8]) = vb;
        }
        __syncthreads();
        int ks = bk >> 5;
        for (int kk = 0; kk < ks; ++kk) {
            bf16x8 a[4], b[4];
#pragma unroll
            for (int m = 0; m < 4; ++m)
                a[m] = *(const bf16x8*)&At[wr * 64 + m * 16 + lr][kk * 32 + lk];
#pragma unroll
            for (int n = 0; n < 4; ++n)
                b[n] = *(const bf16x8*)&Bt[wc * 64 + n * 16 + lr][kk * 32 + lk];
#pragma unroll
            for (int m = 0; m < 4; ++m)
#pragma unroll
                for (int n = 0; n < 4; ++n)
                    acc[m][n] = __builtin_amdgcn_mfma_f32_16x16x32_bf16(a[m], b[n], acc[m][n], 0, 0, 0);
        }
    }
    float bcol[4];
#pragma unroll
    for (int n = 0; n < 4; ++n) bcol[n] = bias[wc * 64 + n * 16 + lr];
    int r0g = (lane >> 4) * 4;
#pragma unroll
    for (int m = 0; m < 4; ++m) {
        int row = base + wr * 64 + m * 16 + r0g;
#pragma unroll
        for (int n = 0; n < 4; ++n) {
            int col = wc * 64 + n * 16 + lr;
#pragma unroll
            for (int r = 0; r < 4; ++r) {
                size_t idx = (size_t)(row + r) * HID + col;
                hb[idx] = f2bf(acc[m][n][r] + bcol[n]);
            }
        }
    }
}

// ===========================================================================
// fused RGCN layer: per 128-dst tile, for each type t: gather-aggregate the
// tile's type-t edges into LDS A-tile (bf16), stage type-t weights, MFMA into
// acc; epilogue relu+bias(+residual) -> hbOut.  hbIn is read-only (ping-pong).
// ===========================================================================
__global__ __launch_bounds__(256) void layer_kernel(
        const int* __restrict__ rp, const int2* __restrict__ erec,
        const unsigned short* __restrict__ hbIn,
        const unsigned short* __restrict__ WTlayer, const float* __restrict__ bias,
        unsigned short* __restrict__ hbOut, int residual) {
    __shared__ unsigned short At[128][136];
    __shared__ unsigned short Bt[128][136];
    int tid = threadIdx.x;
    int base = blockIdx.x * 128;
    int wid = tid >> 6, lane = tid & 63;
    int wr = wid >> 1, wc = wid & 1;
    int lr = lane & 15, lk = (lane >> 4) * 8;
    int sub = lane >> 5, l32 = lane & 31;        // half-wave row split
    int crow = tid >> 1, chalf = tid & 1;        // B staging split
    f32x4 acc[4][4];
#pragma unroll
    for (int m = 0; m < 4; ++m)
#pragma unroll
        for (int n = 0; n < 4; ++n) { acc[m][n][0] = 0.f; acc[m][n][1] = 0.f; acc[m][n][2] = 0.f; acc[m][n][3] = 0.f; }

    for (int t = 0; t < 4; ++t) {
        __syncthreads();   // previous type's MFMA reads done before overwrite
        // ---- stage Bt = WTlayer[c][t*128 .. t*128+128) ----
        {
            const uint4* gb = (const uint4*)(WTlayer + (size_t)crow * KLAY + t * HID + chalf * 64);
            uint4* sb = (uint4*)&Bt[crow][chalf * 64];
#pragma unroll
            for (int i = 0; i < 8; ++i) sb[i] = gb[i];
        }
        // ---- gather-aggregate At rows (2 rows per wave concurrently) ----
        for (int rr = 0; rr < 32; rr += 2) {
            int r = wid * 32 + rr + sub;
            int key = t * N_NODES + base + r;
            int rb = key ? rp[key - 1] : 0;
            int re = rp[key];
            float a0 = 0.f, a1 = 0.f, a2 = 0.f, a3 = 0.f;
            for (int i = rb; i < re; ++i) {
                int2 er = erec[i];
                float nm = __int_as_float(er.y);
                uint2 v = ((const uint2*)(hbIn + (size_t)er.x * HID))[l32];
                a0 += bf2f((unsigned short)(v.x & 0xffffu)) * nm;
                a1 += bf2f((unsigned short)(v.x >> 16)) * nm;
                a2 += bf2f((unsigned short)(v.y & 0xffffu)) * nm;
                a3 += bf2f((unsigned short)(v.y >> 16)) * nm;
            }
            uint2 o; o.x = pack2(a0, a1); o.y = pack2(a2, a3);
            *(uint2*)&At[r][l32 * 4] = o;
        }
        __syncthreads();
        // ---- MFMA this type's 128-k chunk ----
#pragma unroll
        for (int kk = 0; kk < 4; ++kk) {
            bf16x8 a[4], b[4];
#pragma unroll
            for (int m = 0; m < 4; ++m)
                a[m] = *(const bf16x8*)&At[wr * 64 + m * 16 + lr][kk * 32 + lk];
#pragma unroll
            for (int n = 0; n < 4; ++n)
                b[n] = *(const bf16x8*)&Bt[wc * 64 + n * 16 + lr][kk * 32 + lk];
#pragma unroll
            for (int m = 0; m < 4; ++m)
#pragma unroll
                for (int n = 0; n < 4; ++n)
                    acc[m][n] = __builtin_amdgcn_mfma_f32_16x16x32_bf16(a[m], b[n], acc[m][n], 0, 0, 0);
        }
    }
    // ---- epilogue ----
    float bcol[4];
#pragma unroll
    for (int n = 0; n < 4; ++n) bcol[n] = bias[wc * 64 + n * 16 + lr];
    int r0g = (lane >> 4) * 4;
#pragma unroll
    for (int m = 0; m < 4; ++m) {
        int row = base + wr * 64 + m * 16 + r0g;
#pragma unroll
        for (int n = 0; n < 4; ++n) {
            int col = wc * 64 + n * 16 + lr;
#pragma unroll
            for (int r = 0; r < 4; ++r) {
                size_t idx = (size_t)(row + r) * HID + col;
                float v = fmaxf(acc[m][n][r] + bcol[n], 0.f);
                if (residual) v += bf2f(hbIn[idx]);
                hbOut[idx] = f2bf(v);
            }
        }
    }
}

// ===========================================================================
// predict (h in bf16)
// ===========================================================================
__global__ void predict_kernel(const unsigned short* __restrict__ hb,
                               const int* __restrict__ pred_idx,
                               const float* __restrict__ Wb, const float* __restrict__ bbp,
                               float* __restrict__ out) {
    int b = blockIdx.x;
    int tid = threadIdx.x;
    __shared__ float hp[PPG * HID];
    __shared__ float pool[HID];
    __shared__ float vv[HID];
    __shared__ float sc[PPG];
    __shared__ float lse;
    for (int k = tid; k < PPG * HID; k += 256) {
        int p = k >> 7, j = k & 127;
        int node = pred_idx[b * PPG + p];
        hp[k] = bf2f(hb[(size_t)node * HID + j]);
    }
    __syncthreads();
    if (tid < HID) {
        float s = 0.f;
        for (int p = 0; p < PPG; ++p) s += hp[p * HID + tid];
        pool[tid] = s * (1.0f / PPG);
    }
    __syncthreads();
    if (tid < HID) {
        float s = 0.f;
        for (int k = 0; k < HID; ++k) s += Wb[tid * HID + k] * pool[k];
        vv[tid] = s;
    }
    __syncthreads();
    if (tid < PPG) {
        float s = bbp[0];
        for (int j = 0; j < HID; ++j) s += hp[tid * HID + j] * vv[j];
        sc[tid] = s;
    }
    __syncthreads();
    if (tid == 0) {
        float m = -INFINITY;
        for (int p = 0; p < PPG; ++p) m = fmaxf(m, sc[p]);
        float se = 0.f;
        for (int p = 0; p < PPG; ++p) se += expf(sc[p] - m);
        lse = m + logf(se);
    }
    __syncthreads();
    if (tid < PPG) out[b * PPG + tid] = sc[tid] - lse;
}

extern "C" void kernel_launch(void* const* d_in, const int* in_sizes, int n_in,
                              void* d_out, int out_size, void* d_ws, size_t ws_size,
                              hipStream_t stream) {
    const float* emb_table  = (const float*)d_in[0];
    const float* W_t        = (const float*)d_in[1];
    const float* b_t        = (const float*)d_in[2];
    const float* W_r        = (const float*)d_in[3];
    const float* b_r        = (const float*)d_in[4];
    const float* Wb         = (const float*)d_in[5];
    const float* bb         = (const float*)d_in[6];
    const float* norm       = (const float*)d_in[7];
    const int*   global_id  = (const int*)d_in[8];
    const int*   spo        = (const int*)d_in[9];
    const int*   access     = (const int*)d_in[10];
    const int*   pre_access = (const int*)d_in[11];
    const int*   src        = (const int*)d_in[12];
    const int*   dst        = (const int*)d_in[13];
    const int*   etype      = (const int*)d_in[14];
    const int*   pred_idx   = (const int*)d_in[15];
    float* out = (float*)d_out;

    char* ws = (char*)d_ws;
    size_t off = 0;
    unsigned short* hbA  = (unsigned short*)(ws + off); off += (size_t)N_NODES * HID * 2;    // 32 MiB
    unsigned short* hbB  = (unsigned short*)(ws + off); off += (size_t)N_NODES * HID * 2;    // 32 MiB
    unsigned short* A0   = (unsigned short*)(ws + off); off += (size_t)N_NODES * KPROJ * 2;  // 40 MiB
    int*   rp    = (int*)(ws + off);   off += (size_t)NKEYS * 4;
    int*   tsum  = (int*)(ws + off);   off += (size_t)NTILES * 4;
    int2*  erec  = (int2*)(ws + off);  off += (size_t)N_EDGES * 8;                           // 8 MiB
    unsigned short* WTp = (unsigned short*)(ws + off); off += (size_t)HID * KPROJ * 2;
    unsigned short* WTl = (unsigned short*)(ws + off); off += (size_t)2 * HID * KLAY * 2;

    // ---- CSR build ----
    hipMemsetAsync(rp, 0, (size_t)NKEYS * 4, stream);
    count_kernel<<<N_EDGES / 256, 256, 0, stream>>>(dst, etype, rp);
    scan_tile_kernel<<<NTILES, 256, 0, stream>>>(rp, tsum);
    scan_tsum_kernel<<<1, 256, 0, stream>>>(tsum);
    scan_add_kernel<<<NTILES, 256, 0, stream>>>(rp, tsum);
    scatter_kernel<<<N_EDGES / 256, 256, 0, stream>>>(src, dst, etype, norm, rp, erec);

    // ---- weights to bf16 transposed ----
    wtrans_kernel<<<74, 256, 0, stream>>>(W_t, W_r, WTp, WTl);

    // ---- init aggregation + A0 build, then proj GEMM -> hbA ----
    prep_kernel<<<N_NODES / 4, 256, 0, stream>>>(rp, erec, global_id, spo,
                                                 access, pre_access, emb_table, A0);
    gemm_kernel<<<N_NODES / 128, 256, 0, stream>>>(A0, KPROJ, WTp, b_t, hbA);

    // ---- fused RGCN layers (ping-pong hbA/hbB) ----
    layer_kernel<<<N_NODES / 128, 256, 0, stream>>>(rp, erec, hbA, WTl, b_r, hbB, 1);
    layer_kernel<<<N_NODES / 128, 256, 0, stream>>>(rp, erec, hbB, WTl + (size_t)HID * KLAY,
                                                    b_r + HID, hbA, 0);

    predict_kernel<<<NB, 256, 0, stream>>>(hbA, pred_idx, Wb, bb, out);
}

// Round 5
// 674.122 us; speedup vs baseline: 1.3024x; 1.3024x over previous
//
#include <hip/hip_runtime.h>
#include <hip/hip_bf16.h>

#define N_NODES 131072
#define N_EDGES 1048576
#define HID 128
#define NB 512
#define PPG 32
#define NKEYS (4 * N_NODES)
#define NTILES (NKEYS / 256)
#define KPROJ 160              // 133 real K, zero-padded
#define KLAY  512              // 4 types x 128

typedef short bf16x8 __attribute__((ext_vector_type(8)));
typedef float f32x4  __attribute__((ext_vector_type(4)));

__device__ __forceinline__ float bf2f(unsigned short u) {
    return __uint_as_float(((unsigned int)u) << 16);
}
__device__ __forceinline__ unsigned short f2bf(float x) {
    unsigned int u = __float_as_uint(x);
    unsigned int r = ((u >> 16) & 1u) + 0x7fffu;   // RNE
    return (unsigned short)((u + r) >> 16);
}
__device__ __forceinline__ unsigned int pack2(float a, float b) {
    return (unsigned int)f2bf(a) | ((unsigned int)f2bf(b) << 16);
}

// ===========================================================================
// CSR build: key = etype*N + dst; edge payload = int2{src, norm-bits}
// ===========================================================================
__global__ void count_kernel(const int* __restrict__ dst, const int* __restrict__ etype,
                             int* __restrict__ rp) {
    int e = blockIdx.x * blockDim.x + threadIdx.x;
    if (e >= N_EDGES) return;
    atomicAdd(rp + etype[e] * N_NODES + dst[e], 1);
}

__global__ void scan_tile_kernel(int* __restrict__ rp, int* __restrict__ tsum) {
    __shared__ int s[256];
    int g = blockIdx.x * 256 + threadIdx.x;
    int v = rp[g];
    s[threadIdx.x] = v;
    __syncthreads();
    for (int off = 1; off < 256; off <<= 1) {
        int tv = (threadIdx.x >= off) ? s[threadIdx.x - off] : 0;
        __syncthreads();
        s[threadIdx.x] += tv;
        __syncthreads();
    }
    rp[g] = s[threadIdx.x] - v;
    if (threadIdx.x == 255) tsum[blockIdx.x] = s[255];
}

__global__ void scan_tsum_kernel(int* __restrict__ tsum) {
    __shared__ int s[256];
    int t = threadIdx.x;
    int loc[8]; int sum = 0;
#pragma unroll
    for (int i = 0; i < 8; ++i) { loc[i] = tsum[t * 8 + i]; sum += loc[i]; }
    s[t] = sum;
    __syncthreads();
    for (int off = 1; off < 256; off <<= 1) {
        int tv = (t >= off) ? s[t - off] : 0;
        __syncthreads();
        s[t] += tv;
        __syncthreads();
    }
    int run = s[t] - sum;
#pragma unroll
    for (int i = 0; i < 8; ++i) { int v = loc[i]; tsum[t * 8 + i] = run; run += v; }
}

__global__ void scan_add_kernel(int* __restrict__ rp, const int* __restrict__ tsum) {
    int g = blockIdx.x * 256 + threadIdx.x;
    rp[g] += tsum[g >> 8];
}

__global__ void scatter_kernel(const int* __restrict__ src, const int* __restrict__ dst,
                               const int* __restrict__ etype, const float* __restrict__ norm,
                               int* __restrict__ rp, int2* __restrict__ erec) {
    int e = blockIdx.x * blockDim.x + threadIdx.x;
    if (e >= N_EDGES) return;
    int key = etype[e] * N_NODES + dst[e];
    int pos = atomicAdd(rp + key, 1);
    erec[pos] = make_int2(src[e], __float_as_int(norm[e]));
}

// ===========================================================================
// Weight pre-transpose to bf16 [outcol][k] layout.
// ===========================================================================
__global__ void wtrans_kernel(const float* __restrict__ W_t, const float* __restrict__ W_r,
                              unsigned short* __restrict__ WTp, unsigned short* __restrict__ WTl) {
    int u = blockIdx.x * 256 + threadIdx.x;
    if (u < 2560) {                       // proj: 128 cols x 20 kgroups
        int c = u / 20, k0 = (u % 20) * 8;
#pragma unroll
        for (int j = 0; j < 8; ++j) {
            int k = k0 + j;
            float v = (k < 133) ? W_t[k * HID + c] : 0.f;
            WTp[c * KPROJ + k] = f2bf(v);
        }
    } else if (u < 2560 + 16384) {        // layers: 2 x 128 cols x 64 kgroups
        int v = u - 2560;
        int l = v / 8192; int rr = v % 8192;
        int c = rr / 64; int k0 = (rr % 64) * 8;
#pragma unroll
        for (int j = 0; j < 8; ++j) {
            int k = k0 + j; int t = k >> 7; int i = k & 127;
            float w = W_r[(((size_t)(l * 4 + t) * HID) + i) * HID + c];
            WTl[((size_t)l * HID + c) * KLAY + k] = f2bf(w);
        }
    }
}

// ===========================================================================
// prep: build A0[N][160] bf16 = concat(emb', feats, zeros).  wave per node;
// 2 groups x 32 lanes x float4 -> 2 edges gathered concurrently.
// ===========================================================================
__global__ __launch_bounds__(256) void prep_kernel(
        const int* __restrict__ rp, const int2* __restrict__ erec,
        const int* __restrict__ gid,
        const int* __restrict__ spo, const int* __restrict__ access,
        const int* __restrict__ pre, const float* __restrict__ emb,
        unsigned short* __restrict__ A0) {
    int wave = threadIdx.x >> 6, lane = threadIdx.x & 63;
    int n = blockIdx.x * 4 + wave;
    int g = lane >> 5, sl = lane & 31;
    int s0 = spo[n * 3], s1 = spo[n * 3 + 1], s2 = spo[n * 3 + 2];
    int rb = n ? rp[n - 1] : 0, re = rp[n];
    float a0 = 0.f, a1 = 0.f, a2 = 0.f, a3 = 0.f;
    if ((s0 + s2) > 0 && re > rb) {
        for (int i = rb + g; i < re; i += 2) {
            int2 er = erec[i];
            float nm = __int_as_float(er.y);
            float4 v = ((const float4*)(emb + (size_t)gid[er.x] * HID))[sl];
            a0 += v.x * nm; a1 += v.y * nm; a2 += v.z * nm; a3 += v.w * nm;
        }
        a0 += __shfl_xor(a0, 32, 64);
        a1 += __shfl_xor(a1, 32, 64);
        a2 += __shfl_xor(a2, 32, 64);
        a3 += __shfl_xor(a3, 32, 64);
    } else if (g == 0) {
        float4 v = ((const float4*)(emb + (size_t)gid[n] * HID))[sl];
        a0 = v.x; a1 = v.y; a2 = v.z; a3 = v.w;
    }
    unsigned int* row = (unsigned int*)(A0 + (size_t)n * KPROJ);
    if (g == 0) {
        uint2 o; o.x = pack2(a0, a1); o.y = pack2(a2, a3);
        *(uint2*)(row + sl * 2) = o;
    }
    if (lane < 16) {
        int c0 = 128 + lane * 2;
        float f0 = 0.f, f1 = 0.f;
        if (c0 == 128)      { f0 = (float)s0;      f1 = (float)s1; }
        else if (c0 == 130) { f0 = (float)s2;      f1 = (float)access[n]; }
        else if (c0 == 132) { f0 = (float)pre[n];  f1 = 0.f; }
        row[64 + lane] = pack2(f0, f1);
    }
}

// ===========================================================================
// aggregation: wave per (type,dst) key; 4 groups x 16 lanes x uint4 ->
// 4 edges' full 256B rows gathered concurrently; shfl-tree reduce; lanes of
// group 0 write the 256B chunk Aagg[d][t*128 ..].
// ===========================================================================
__global__ __launch_bounds__(256) void agg_kernel(
        const int* __restrict__ rp, const int2* __restrict__ erec,
        const unsigned short* __restrict__ hb, unsigned short* __restrict__ Aagg) {
    int wave = threadIdx.x >> 6, lane = threadIdx.x & 63;
    int key = blockIdx.x * 4 + wave;
    int t = key >> 17;                  // key / N_NODES (N = 2^17)
    int d = key & (N_NODES - 1);
    int g = lane >> 4, sl = lane & 15;
    int rb = key ? rp[key - 1] : 0;
    int re = rp[key];
    float a[8] = {0.f, 0.f, 0.f, 0.f, 0.f, 0.f, 0.f, 0.f};
    for (int i = rb + g; i < re; i += 4) {
        int2 er = erec[i];
        float nm = __int_as_float(er.y);
        uint4 v = ((const uint4*)(hb + (size_t)er.x * HID))[sl];
        a[0] += bf2f((unsigned short)(v.x & 0xffffu)) * nm;
        a[1] += bf2f((unsigned short)(v.x >> 16)) * nm;
        a[2] += bf2f((unsigned short)(v.y & 0xffffu)) * nm;
        a[3] += bf2f((unsigned short)(v.y >> 16)) * nm;
        a[4] += bf2f((unsigned short)(v.z & 0xffffu)) * nm;
        a[5] += bf2f((unsigned short)(v.z >> 16)) * nm;
        a[6] += bf2f((unsigned short)(v.w & 0xffffu)) * nm;
        a[7] += bf2f((unsigned short)(v.w >> 16)) * nm;
    }
#pragma unroll
    for (int k = 0; k < 8; ++k) {
        a[k] += __shfl_xor(a[k], 16, 64);
        a[k] += __shfl_xor(a[k], 32, 64);
    }
    if (g == 0) {
        uint4 o;
        o.x = pack2(a[0], a[1]); o.y = pack2(a[2], a[3]);
        o.z = pack2(a[4], a[5]); o.w = pack2(a[6], a[7]);
        ((uint4*)(Aagg + (size_t)d * KLAY + t * HID))[sl] = o;
    }
}

// ===========================================================================
// MFMA GEMM: C[128-tile][128] = A[N][K]_bf16 @ WT^T (+bias, mode epilogue)
// mode 0: out = acc+b            (proj)
// mode 1: out = relu(acc+b)+hb   (layer 0, residual; hb read+write same elem)
// mode 2: out = relu(acc+b)      (layer 1)
// ===========================================================================
__global__ __launch_bounds__(256) void gemm_kernel(
        const unsigned short* __restrict__ A, int K,
        const unsigned short* __restrict__ WT, const float* __restrict__ bias,
        unsigned short* __restrict__ hb, int mode) {
    __shared__ unsigned short At[128][136];
    __shared__ unsigned short Bt[128][136];
    int tid = threadIdx.x;
    int base = blockIdx.x * 128;
    int wid = tid >> 6, lane = tid & 63;
    int wr = wid >> 1, wc = wid & 1;
    int lr = lane & 15, lk = (lane >> 4) * 8;
    f32x4 acc[4][4];
#pragma unroll
    for (int m = 0; m < 4; ++m)
#pragma unroll
        for (int n = 0; n < 4; ++n) { acc[m][n][0] = 0.f; acc[m][n][1] = 0.f; acc[m][n][2] = 0.f; acc[m][n][3] = 0.f; }
    int row2 = tid >> 1, half = tid & 1;
    for (int k0 = 0; k0 < K; k0 += 128) {
        int bk = K - k0; if (bk > 128) bk = 128;
        int hw = bk >> 1;
        int nld = bk >> 4;
        const unsigned short* ga = A  + (size_t)(base + row2) * K + k0 + half * hw;
        const unsigned short* gb = WT + (size_t)row2 * K + k0 + half * hw;
        __syncthreads();
        for (int i = 0; i < nld; ++i) {
            uint4 va = ((const uint4*)ga)[i];
            *((uint4*)&At[row2][half * hw + i * 8]) = va;
            uint4 vb = ((const uint4*)gb)[i];
            *((uint4*)&Bt[row2][half * hw + i * 8]) = vb;
        }
        __syncthreads();
        int ks = bk >> 5;
        for (int kk = 0; kk < ks; ++kk) {
            bf16x8 a[4], b[4];
#pragma unroll
            for (int m = 0; m < 4; ++m)
                a[m] = *(const bf16x8*)&At[wr * 64 + m * 16 + lr][kk * 32 + lk];
#pragma unroll
            for (int n = 0; n < 4; ++n)
                b[n] = *(const bf16x8*)&Bt[wc * 64 + n * 16 + lr][kk * 32 + lk];
#pragma unroll
            for (int m = 0; m < 4; ++m)
#pragma unroll
                for (int n = 0; n < 4; ++n)
                    acc[m][n] = __builtin_amdgcn_mfma_f32_16x16x32_bf16(a[m], b[n], acc[m][n], 0, 0, 0);
        }
    }
    float bcol[4];
#pragma unroll
    for (int n = 0; n < 4; ++n) bcol[n] = bias[wc * 64 + n * 16 + lr];
    int r0g = (lane >> 4) * 4;
#pragma unroll
    for (int m = 0; m < 4; ++m) {
        int row = base + wr * 64 + m * 16 + r0g;
#pragma unroll
        for (int n = 0; n < 4; ++n) {
            int col = wc * 64 + n * 16 + lr;
#pragma unroll
            for (int r = 0; r < 4; ++r) {
                float v = acc[m][n][r] + bcol[n];
                size_t idx = (size_t)(row + r) * HID + col;
                if (mode == 1)      v = fmaxf(v, 0.f) + bf2f(hb[idx]);
                else if (mode == 2) v = fmaxf(v, 0.f);
                hb[idx] = f2bf(v);
            }
        }
    }
}

// ===========================================================================
// predict (h in bf16)
// ===========================================================================
__global__ void predict_kernel(const unsigned short* __restrict__ hb,
                               const int* __restrict__ pred_idx,
                               const float* __restrict__ Wb, const float* __restrict__ bbp,
                               float* __restrict__ out) {
    int b = blockIdx.x;
    int tid = threadIdx.x;
    __shared__ float hp[PPG * HID];
    __shared__ float pool[HID];
    __shared__ float vv[HID];
    __shared__ float sc[PPG];
    __shared__ float lse;
    for (int k = tid; k < PPG * HID; k += 256) {
        int p = k >> 7, j = k & 127;
        int node = pred_idx[b * PPG + p];
        hp[k] = bf2f(hb[(size_t)node * HID + j]);
    }
    __syncthreads();
    if (tid < HID) {
        float s = 0.f;
        for (int p = 0; p < PPG; ++p) s += hp[p * HID + tid];
        pool[tid] = s * (1.0f / PPG);
    }
    __syncthreads();
    if (tid < HID) {
        float s = 0.f;
        for (int k = 0; k < HID; ++k) s += Wb[tid * HID + k] * pool[k];
        vv[tid] = s;
    }
    __syncthreads();
    if (tid < PPG) {
        float s = bbp[0];
        for (int j = 0; j < HID; ++j) s += hp[tid * HID + j] * vv[j];
        sc[tid] = s;
    }
    __syncthreads();
    if (tid == 0) {
        float m = -INFINITY;
        for (int p = 0; p < PPG; ++p) m = fmaxf(m, sc[p]);
        float se = 0.f;
        for (int p = 0; p < PPG; ++p) se += expf(sc[p] - m);
        lse = m + logf(se);
    }
    __syncthreads();
    if (tid < PPG) out[b * PPG + tid] = sc[tid] - lse;
}

extern "C" void kernel_launch(void* const* d_in, const int* in_sizes, int n_in,
                              void* d_out, int out_size, void* d_ws, size_t ws_size,
                              hipStream_t stream) {
    const float* emb_table  = (const float*)d_in[0];
    const float* W_t        = (const float*)d_in[1];
    const float* b_t        = (const float*)d_in[2];
    const float* W_r        = (const float*)d_in[3];
    const float* b_r        = (const float*)d_in[4];
    const float* Wb         = (const float*)d_in[5];
    const float* bb         = (const float*)d_in[6];
    const float* norm       = (const float*)d_in[7];
    const int*   global_id  = (const int*)d_in[8];
    const int*   spo        = (const int*)d_in[9];
    const int*   access     = (const int*)d_in[10];
    const int*   pre_access = (const int*)d_in[11];
    const int*   src        = (const int*)d_in[12];
    const int*   dst        = (const int*)d_in[13];
    const int*   etype      = (const int*)d_in[14];
    const int*   pred_idx   = (const int*)d_in[15];
    float* out = (float*)d_out;

    char* ws = (char*)d_ws;
    size_t off = 0;
    unsigned short* hb   = (unsigned short*)(ws + off); off += (size_t)N_NODES * HID * 2;      // 32 MiB
    unsigned short* Abuf = (unsigned short*)(ws + off); off += (size_t)N_NODES * KLAY * 2;     // 128 MiB (A0 aliases)
    int*   rp    = (int*)(ws + off);   off += (size_t)NKEYS * 4;
    int*   tsum  = (int*)(ws + off);   off += (size_t)NTILES * 4;
    int2*  erec  = (int2*)(ws + off);  off += (size_t)N_EDGES * 8;
    unsigned short* WTp = (unsigned short*)(ws + off); off += (size_t)HID * KPROJ * 2;
    unsigned short* WTl = (unsigned short*)(ws + off); off += (size_t)2 * HID * KLAY * 2;
    unsigned short* A0 = Abuf;   // [N][KPROJ], consumed before Aagg overwrites

    // ---- CSR build ----
    hipMemsetAsync(rp, 0, (size_t)NKEYS * 4, stream);
    count_kernel<<<N_EDGES / 256, 256, 0, stream>>>(dst, etype, rp);
    scan_tile_kernel<<<NTILES, 256, 0, stream>>>(rp, tsum);
    scan_tsum_kernel<<<1, 256, 0, stream>>>(tsum);
    scan_add_kernel<<<NTILES, 256, 0, stream>>>(rp, tsum);
    scatter_kernel<<<N_EDGES / 256, 256, 0, stream>>>(src, dst, etype, norm, rp, erec);

    // ---- weights to bf16 transposed ----
    wtrans_kernel<<<74, 256, 0, stream>>>(W_t, W_r, WTp, WTl);

    // ---- init aggregation + A0 build, then proj GEMM -> hb ----
    prep_kernel<<<N_NODES / 4, 256, 0, stream>>>(rp, erec, global_id, spo,
                                                 access, pre_access, emb_table, A0);
    gemm_kernel<<<N_NODES / 128, 256, 0, stream>>>(A0, KPROJ, WTp, b_t, hb, 0);

    // ---- RGCN layers: aggregate-then-transform ----
    agg_kernel<<<NKEYS / 4, 256, 0, stream>>>(rp, erec, hb, Abuf);
    gemm_kernel<<<N_NODES / 128, 256, 0, stream>>>(Abuf, KLAY, WTl, b_r, hb, 1);
    agg_kernel<<<NKEYS / 4, 256, 0, stream>>>(rp, erec, hb, Abuf);
    gemm_kernel<<<N_NODES / 128, 256, 0, stream>>>(Abuf, KLAY, WTl + (size_t)HID * KLAY,
                                                   b_r + HID, hb, 2);

    predict_kernel<<<NB, 256, 0, stream>>>(hb, pred_idx, Wb, bb, out);
}

// Round 6
// 557.532 us; speedup vs baseline: 1.5748x; 1.2091x over previous
//
#include <hip/hip_runtime.h>
#include <hip/hip_bf16.h>

#define N_NODES 131072
#define N_EDGES 1048576
#define HID 128
#define NB 512
#define PPG 32
#define NKEYS (4 * N_NODES)
#define NTILES (NKEYS / 256)
#define KPROJ 160              // 133 real K, zero-padded (chunks 128 + 32)
#define KLAY  512              // 4 types x 128

typedef short bf16x8 __attribute__((ext_vector_type(8)));
typedef float f32x4  __attribute__((ext_vector_type(4)));
typedef unsigned int u32x4 __attribute__((ext_vector_type(4)));

__device__ __forceinline__ float bf2f(unsigned short u) {
    return __uint_as_float(((unsigned int)u) << 16);
}
__device__ __forceinline__ unsigned short f2bf(float x) {
    unsigned int u = __float_as_uint(x);
    unsigned int r = ((u >> 16) & 1u) + 0x7fffu;   // RNE
    return (unsigned short)((u + r) >> 16);
}
__device__ __forceinline__ unsigned int pack2(float a, float b) {
    return (unsigned int)f2bf(a) | ((unsigned int)f2bf(b) << 16);
}

// ===========================================================================
// CSR build: key = etype*N + dst; edge payload = int2{src, norm-bits}
// ===========================================================================
__global__ void count_kernel(const int* __restrict__ dst, const int* __restrict__ etype,
                             int* __restrict__ rp) {
    int e = blockIdx.x * blockDim.x + threadIdx.x;
    if (e >= N_EDGES) return;
    atomicAdd(rp + etype[e] * N_NODES + dst[e], 1);
}

__global__ void scan_tile_kernel(int* __restrict__ rp, int* __restrict__ tsum) {
    __shared__ int s[256];
    int g = blockIdx.x * 256 + threadIdx.x;
    int v = rp[g];
    s[threadIdx.x] = v;
    __syncthreads();
    for (int off = 1; off < 256; off <<= 1) {
        int tv = (threadIdx.x >= off) ? s[threadIdx.x - off] : 0;
        __syncthreads();
        s[threadIdx.x] += tv;
        __syncthreads();
    }
    rp[g] = s[threadIdx.x] - v;
    if (threadIdx.x == 255) tsum[blockIdx.x] = s[255];
}

__global__ void scan_tsum_kernel(int* __restrict__ tsum) {
    __shared__ int s[256];
    int t = threadIdx.x;
    int loc[8]; int sum = 0;
#pragma unroll
    for (int i = 0; i < 8; ++i) { loc[i] = tsum[t * 8 + i]; sum += loc[i]; }
    s[t] = sum;
    __syncthreads();
    for (int off = 1; off < 256; off <<= 1) {
        int tv = (t >= off) ? s[t - off] : 0;
        __syncthreads();
        s[t] += tv;
        __syncthreads();
    }
    int run = s[t] - sum;
#pragma unroll
    for (int i = 0; i < 8; ++i) { int v = loc[i]; tsum[t * 8 + i] = run; run += v; }
}

__global__ void scan_add_kernel(int* __restrict__ rp, const int* __restrict__ tsum) {
    int g = blockIdx.x * 256 + threadIdx.x;
    rp[g] += tsum[g >> 8];
}

__global__ void scatter_kernel(const int* __restrict__ src, const int* __restrict__ dst,
                               const int* __restrict__ etype, const float* __restrict__ norm,
                               int* __restrict__ rp, int2* __restrict__ erec) {
    int e = blockIdx.x * blockDim.x + threadIdx.x;
    if (e >= N_EDGES) return;
    int key = etype[e] * N_NODES + dst[e];
    int pos = atomicAdd(rp + key, 1);
    erec[pos] = make_int2(src[e], __float_as_int(norm[e]));
}

// ===========================================================================
// Weight pre-transpose to bf16 [outcol][k] layout.
// ===========================================================================
__global__ void wtrans_kernel(const float* __restrict__ W_t, const float* __restrict__ W_r,
                              unsigned short* __restrict__ WTp, unsigned short* __restrict__ WTl) {
    int u = blockIdx.x * 256 + threadIdx.x;
    if (u < 2560) {                       // proj: 128 cols x 20 kgroups
        int c = u / 20, k0 = (u % 20) * 8;
#pragma unroll
        for (int j = 0; j < 8; ++j) {
            int k = k0 + j;
            float v = (k < 133) ? W_t[k * HID + c] : 0.f;
            WTp[c * KPROJ + k] = f2bf(v);
        }
    } else if (u < 2560 + 16384) {        // layers: 2 x 128 cols x 64 kgroups
        int v = u - 2560;
        int l = v / 8192; int rr = v % 8192;
        int c = rr / 64; int k0 = (rr % 64) * 8;
#pragma unroll
        for (int j = 0; j < 8; ++j) {
            int k = k0 + j; int t = k >> 7; int i = k & 127;
            float w = W_r[(((size_t)(l * 4 + t) * HID) + i) * HID + c];
            WTl[((size_t)l * HID + c) * KLAY + k] = f2bf(w);
        }
    }
}

// ===========================================================================
// prep: build A0[N][160] bf16 = concat(emb', feats, zeros).  wave per node;
// 2 groups x 32 lanes x float4 -> 2 edges gathered concurrently.
// ===========================================================================
__global__ __launch_bounds__(256) void prep_kernel(
        const int* __restrict__ rp, const int2* __restrict__ erec,
        const int* __restrict__ gid,
        const int* __restrict__ spo, const int* __restrict__ access,
        const int* __restrict__ pre, const float* __restrict__ emb,
        unsigned short* __restrict__ A0) {
    int wave = threadIdx.x >> 6, lane = threadIdx.x & 63;
    int n = blockIdx.x * 4 + wave;
    int g = lane >> 5, sl = lane & 31;
    int s0 = spo[n * 3], s1 = spo[n * 3 + 1], s2 = spo[n * 3 + 2];
    int rb = n ? rp[n - 1] : 0, re = rp[n];
    float a0 = 0.f, a1 = 0.f, a2 = 0.f, a3 = 0.f;
    if ((s0 + s2) > 0 && re > rb) {
        for (int i = rb + g; i < re; i += 2) {
            int2 er = erec[i];
            float nm = __int_as_float(er.y);
            float4 v = ((const float4*)(emb + (size_t)gid[er.x] * HID))[sl];
            a0 += v.x * nm; a1 += v.y * nm; a2 += v.z * nm; a3 += v.w * nm;
        }
        a0 += __shfl_xor(a0, 32, 64);
        a1 += __shfl_xor(a1, 32, 64);
        a2 += __shfl_xor(a2, 32, 64);
        a3 += __shfl_xor(a3, 32, 64);
    } else if (g == 0) {
        float4 v = ((const float4*)(emb + (size_t)gid[n] * HID))[sl];
        a0 = v.x; a1 = v.y; a2 = v.z; a3 = v.w;
    }
    unsigned int* row = (unsigned int*)(A0 + (size_t)n * KPROJ);
    if (g == 0) {
        uint2 o; o.x = pack2(a0, a1); o.y = pack2(a2, a3);
        *(uint2*)(row + sl * 2) = o;
    }
    if (lane < 16) {
        int c0 = 128 + lane * 2;
        float f0 = 0.f, f1 = 0.f;
        if (c0 == 128)      { f0 = (float)s0;      f1 = (float)s1; }
        else if (c0 == 130) { f0 = (float)s2;      f1 = (float)access[n]; }
        else if (c0 == 132) { f0 = (float)pre[n];  f1 = 0.f; }
        row[64 + lane] = pack2(f0, f1);
    }
}

// ===========================================================================
// aggregation: wave per dst; 4 groups of 16 lanes, one per edge type.
// Each group serially (unroll-2) accumulates its (t,d) segment: lane owns 8
// output elements (uint4 of the 256B row chunk).  No cross-lane reduce.
// ===========================================================================
__device__ __forceinline__ void acc8(float* a, u32x4 v, float nm) {
    a[0] = fmaf(bf2f((unsigned short)(v.x & 0xffffu)), nm, a[0]);
    a[1] = fmaf(bf2f((unsigned short)(v.x >> 16)),     nm, a[1]);
    a[2] = fmaf(bf2f((unsigned short)(v.y & 0xffffu)), nm, a[2]);
    a[3] = fmaf(bf2f((unsigned short)(v.y >> 16)),     nm, a[3]);
    a[4] = fmaf(bf2f((unsigned short)(v.z & 0xffffu)), nm, a[4]);
    a[5] = fmaf(bf2f((unsigned short)(v.z >> 16)),     nm, a[5]);
    a[6] = fmaf(bf2f((unsigned short)(v.w & 0xffffu)), nm, a[6]);
    a[7] = fmaf(bf2f((unsigned short)(v.w >> 16)),     nm, a[7]);
}

__global__ __launch_bounds__(256) void agg_kernel(
        const int* __restrict__ rp, const int2* __restrict__ erec,
        const unsigned short* __restrict__ hb, unsigned short* __restrict__ Aagg) {
    int wave = threadIdx.x >> 6, lane = threadIdx.x & 63;
    int d = blockIdx.x * 4 + wave;
    int t = lane >> 4, sl = lane & 15;
    int key = t * N_NODES + d;
    int rb = key ? rp[key - 1] : 0;
    int re = rp[key];
    float a[8] = {0.f, 0.f, 0.f, 0.f, 0.f, 0.f, 0.f, 0.f};
    int i = rb;
    for (; i + 2 <= re; i += 2) {
        int2 e0 = erec[i];
        int2 e1 = erec[i + 1];
        u32x4 v0 = *((const u32x4*)(hb + (size_t)e0.x * HID) + sl);
        u32x4 v1 = *((const u32x4*)(hb + (size_t)e1.x * HID) + sl);
        acc8(a, v0, __int_as_float(e0.y));
        acc8(a, v1, __int_as_float(e1.y));
    }
    if (i < re) {
        int2 e0 = erec[i];
        u32x4 v0 = *((const u32x4*)(hb + (size_t)e0.x * HID) + sl);
        acc8(a, v0, __int_as_float(e0.y));
    }
    u32x4 o;
    o.x = pack2(a[0], a[1]); o.y = pack2(a[2], a[3]);
    o.z = pack2(a[4], a[5]); o.w = pack2(a[6], a[7]);
    __builtin_nontemporal_store(o, (u32x4*)(Aagg + (size_t)d * KLAY + t * HID) + sl);
}

// ===========================================================================
// MFMA GEMM with global_load_lds staging (m97 structure, linear LDS).
// C[128-tile][128] = A[N][K]_bf16 @ WT^T (+bias, mode epilogue)
// mode 0: out = acc+b; 1: relu(acc+b)+hb (residual); 2: relu(acc+b)
// ===========================================================================
__device__ __forceinline__ void stage_tile(const unsigned short* gbase, int ldK,
                                           int k0, int bk, unsigned short* lds,
                                           int wid, int lane) {
    int iters = bk >> 4;                          // 128*bk*2 / 4096
    int sh = (bk == 128) ? 4 : (bk == 64 ? 3 : 2);
    int msk = (1 << sh) - 1;
    for (int i = 0; i < iters; ++i) {
        int c = (i * 4 + wid) * 64 + lane;
        int row = c >> sh, col16 = c & msk;
        const unsigned short* g = gbase + (size_t)row * ldK + k0 + col16 * 8;
        unsigned short* l = lds + (size_t)(i * 4 + wid) * 512;   // 1 KiB per wave-instr
        __builtin_amdgcn_global_load_lds(
            (const __attribute__((address_space(1))) void*)g,
            (__attribute__((address_space(3))) void*)l, 16, 0, 0);
    }
}

__global__ __launch_bounds__(256) void gemm_kernel(
        const unsigned short* __restrict__ A, int K,
        const unsigned short* __restrict__ WT, const float* __restrict__ bias,
        unsigned short* __restrict__ hb, int mode) {
    __shared__ unsigned short At[128 * 128];
    __shared__ unsigned short Bt[128 * 128];
    int tid = threadIdx.x;
    int base = blockIdx.x * 128;
    int wid = tid >> 6, lane = tid & 63;
    int wr = wid >> 1, wc = wid & 1;
    int lr = lane & 15, lk = (lane >> 4) * 8;
    f32x4 acc[4][4];
#pragma unroll
    for (int m = 0; m < 4; ++m)
#pragma unroll
        for (int n = 0; n < 4; ++n) { acc[m][n][0] = 0.f; acc[m][n][1] = 0.f; acc[m][n][2] = 0.f; acc[m][n][3] = 0.f; }
    const unsigned short* Abase = A + (size_t)base * K;
    for (int k0 = 0; k0 < K; k0 += 128) {
        int bk = K - k0; if (bk > 128) bk = 128;
        __syncthreads();
        stage_tile(Abase, K, k0, bk, At, wid, lane);
        stage_tile(WT,    K, k0, bk, Bt, wid, lane);
        __syncthreads();                 // drains vmcnt(0), data in LDS
        int ks = bk >> 5;
        for (int kk = 0; kk < ks; ++kk) {
            bf16x8 a[4], b[4];
#pragma unroll
            for (int m = 0; m < 4; ++m)
                a[m] = *(const bf16x8*)&At[(wr * 64 + m * 16 + lr) * bk + kk * 32 + lk];
#pragma unroll
            for (int n = 0; n < 4; ++n)
                b[n] = *(const bf16x8*)&Bt[(wc * 64 + n * 16 + lr) * bk + kk * 32 + lk];
#pragma unroll
            for (int m = 0; m < 4; ++m)
#pragma unroll
                for (int n = 0; n < 4; ++n)
                    acc[m][n] = __builtin_amdgcn_mfma_f32_16x16x32_bf16(a[m], b[n], acc[m][n], 0, 0, 0);
        }
    }
    float bcol[4];
#pragma unroll
    for (int n = 0; n < 4; ++n) bcol[n] = bias[wc * 64 + n * 16 + lr];
    int r0g = (lane >> 4) * 4;
#pragma unroll
    for (int m = 0; m < 4; ++m) {
        int row = base + wr * 64 + m * 16 + r0g;
#pragma unroll
        for (int n = 0; n < 4; ++n) {
            int col = wc * 64 + n * 16 + lr;
#pragma unroll
            for (int r = 0; r < 4; ++r) {
                float v = acc[m][n][r] + bcol[n];
                size_t idx = (size_t)(row + r) * HID + col;
                if (mode == 1)      v = fmaxf(v, 0.f) + bf2f(hb[idx]);
                else if (mode == 2) v = fmaxf(v, 0.f);
                hb[idx] = f2bf(v);
            }
        }
    }
}

// ===========================================================================
// predict (h in bf16)
// ===========================================================================
__global__ void predict_kernel(const unsigned short* __restrict__ hb,
                               const int* __restrict__ pred_idx,
                               const float* __restrict__ Wb, const float* __restrict__ bbp,
                               float* __restrict__ out) {
    int b = blockIdx.x;
    int tid = threadIdx.x;
    __shared__ float hp[PPG * HID];
    __shared__ float pool[HID];
    __shared__ float vv[HID];
    __shared__ float sc[PPG];
    __shared__ float lse;
    for (int k = tid; k < PPG * HID; k += 256) {
        int p = k >> 7, j = k & 127;
        int node = pred_idx[b * PPG + p];
        hp[k] = bf2f(hb[(size_t)node * HID + j]);
    }
    __syncthreads();
    if (tid < HID) {
        float s = 0.f;
        for (int p = 0; p < PPG; ++p) s += hp[p * HID + tid];
        pool[tid] = s * (1.0f / PPG);
    }
    __syncthreads();
    if (tid < HID) {
        float s = 0.f;
        for (int k = 0; k < HID; ++k) s += Wb[tid * HID + k] * pool[k];
        vv[tid] = s;
    }
    __syncthreads();
    if (tid < PPG) {
        float s = bbp[0];
        for (int j = 0; j < HID; ++j) s += hp[tid * HID + j] * vv[j];
        sc[tid] = s;
    }
    __syncthreads();
    if (tid == 0) {
        float m = -INFINITY;
        for (int p = 0; p < PPG; ++p) m = fmaxf(m, sc[p]);
        float se = 0.f;
        for (int p = 0; p < PPG; ++p) se += expf(sc[p] - m);
        lse = m + logf(se);
    }
    __syncthreads();
    if (tid < PPG) out[b * PPG + tid] = sc[tid] - lse;
}

extern "C" void kernel_launch(void* const* d_in, const int* in_sizes, int n_in,
                              void* d_out, int out_size, void* d_ws, size_t ws_size,
                              hipStream_t stream) {
    const float* emb_table  = (const float*)d_in[0];
    const float* W_t        = (const float*)d_in[1];
    const float* b_t        = (const float*)d_in[2];
    const float* W_r        = (const float*)d_in[3];
    const float* b_r        = (const float*)d_in[4];
    const float* Wb         = (const float*)d_in[5];
    const float* bb         = (const float*)d_in[6];
    const float* norm       = (const float*)d_in[7];
    const int*   global_id  = (const int*)d_in[8];
    const int*   spo        = (const int*)d_in[9];
    const int*   access     = (const int*)d_in[10];
    const int*   pre_access = (const int*)d_in[11];
    const int*   src        = (const int*)d_in[12];
    const int*   dst        = (const int*)d_in[13];
    const int*   etype      = (const int*)d_in[14];
    const int*   pred_idx   = (const int*)d_in[15];
    float* out = (float*)d_out;

    char* ws = (char*)d_ws;
    size_t off = 0;
    unsigned short* hb   = (unsigned short*)(ws + off); off += (size_t)N_NODES * HID * 2;      // 32 MiB
    unsigned short* Abuf = (unsigned short*)(ws + off); off += (size_t)N_NODES * KLAY * 2;     // 128 MiB (A0 aliases)
    int*   rp    = (int*)(ws + off);   off += (size_t)NKEYS * 4;
    int*   tsum  = (int*)(ws + off);   off += (size_t)NTILES * 4;
    int2*  erec  = (int2*)(ws + off);  off += (size_t)N_EDGES * 8;
    unsigned short* WTp = (unsigned short*)(ws + off); off += (size_t)HID * KPROJ * 2;
    unsigned short* WTl = (unsigned short*)(ws + off); off += (size_t)2 * HID * KLAY * 2;
    unsigned short* A0 = Abuf;   // [N][KPROJ], consumed before Aagg overwrites

    // ---- CSR build ----
    hipMemsetAsync(rp, 0, (size_t)NKEYS * 4, stream);
    count_kernel<<<N_EDGES / 256, 256, 0, stream>>>(dst, etype, rp);
    scan_tile_kernel<<<NTILES, 256, 0, stream>>>(rp, tsum);
    scan_tsum_kernel<<<1, 256, 0, stream>>>(tsum);
    scan_add_kernel<<<NTILES, 256, 0, stream>>>(rp, tsum);
    scatter_kernel<<<N_EDGES / 256, 256, 0, stream>>>(src, dst, etype, norm, rp, erec);

    // ---- weights to bf16 transposed ----
    wtrans_kernel<<<74, 256, 0, stream>>>(W_t, W_r, WTp, WTl);

    // ---- init aggregation + A0 build, then proj GEMM -> hb ----
    prep_kernel<<<N_NODES / 4, 256, 0, stream>>>(rp, erec, global_id, spo,
                                                 access, pre_access, emb_table, A0);
    gemm_kernel<<<N_NODES / 128, 256, 0, stream>>>(A0, KPROJ, WTp, b_t, hb, 0);

    // ---- RGCN layers: aggregate-then-transform ----
    agg_kernel<<<N_NODES / 4, 256, 0, stream>>>(rp, erec, hb, Abuf);
    gemm_kernel<<<N_NODES / 128, 256, 0, stream>>>(Abuf, KLAY, WTl, b_r, hb, 1);
    agg_kernel<<<N_NODES / 4, 256, 0, stream>>>(rp, erec, hb, Abuf);
    gemm_kernel<<<N_NODES / 128, 256, 0, stream>>>(Abuf, KLAY, WTl + (size_t)HID * KLAY,
                                                   b_r + HID, hb, 2);

    predict_kernel<<<NB, 256, 0, stream>>>(hb, pred_idx, Wb, bb, out);
}

// Round 8
// 535.673 us; speedup vs baseline: 1.6390x; 1.0408x over previous
//
#include <hip/hip_runtime.h>
#include <hip/hip_bf16.h>

#define N_NODES 131072
#define N_EDGES 1048576
#define HID 128
#define NB 512
#define PPG 32
#define NKEYS (4 * N_NODES)
#define NTILES (NKEYS / 256)
#define KPROJ 160              // 133 real K, zero-padded (chunks 64+64+32)
#define KLAY  512              // 4 types x 128

typedef short bf16x8 __attribute__((ext_vector_type(8)));
typedef float f32x4  __attribute__((ext_vector_type(4)));
typedef unsigned int u32x4 __attribute__((ext_vector_type(4)));

__device__ __forceinline__ float bf2f(unsigned short u) {
    return __uint_as_float(((unsigned int)u) << 16);
}
__device__ __forceinline__ unsigned short f2bf(float x) {
    unsigned int u = __float_as_uint(x);
    unsigned int r = ((u >> 16) & 1u) + 0x7fffu;   // RNE
    return (unsigned short)((u + r) >> 16);
}
__device__ __forceinline__ unsigned int pack2(float a, float b) {
    return (unsigned int)f2bf(a) | ((unsigned int)f2bf(b) << 16);
}

// ===========================================================================
// CSR build: key = etype*N + dst; edge payload = int2{src, norm-bits}
// ===========================================================================
__global__ void count_kernel(const int* __restrict__ dst, const int* __restrict__ etype,
                             int* __restrict__ rp) {
    int e = blockIdx.x * blockDim.x + threadIdx.x;
    if (e >= N_EDGES) return;
    atomicAdd(rp + etype[e] * N_NODES + dst[e], 1);
}

__global__ void scan_tile_kernel(int* __restrict__ rp, int* __restrict__ tsum) {
    __shared__ int s[256];
    int g = blockIdx.x * 256 + threadIdx.x;
    int v = rp[g];
    s[threadIdx.x] = v;
    __syncthreads();
    for (int off = 1; off < 256; off <<= 1) {
        int tv = (threadIdx.x >= off) ? s[threadIdx.x - off] : 0;
        __syncthreads();
        s[threadIdx.x] += tv;
        __syncthreads();
    }
    rp[g] = s[threadIdx.x] - v;
    if (threadIdx.x == 255) tsum[blockIdx.x] = s[255];
}

__global__ void scan_tsum_kernel(int* __restrict__ tsum) {
    __shared__ int s[256];
    int t = threadIdx.x;
    int loc[8]; int sum = 0;
#pragma unroll
    for (int i = 0; i < 8; ++i) { loc[i] = tsum[t * 8 + i]; sum += loc[i]; }
    s[t] = sum;
    __syncthreads();
    for (int off = 1; off < 256; off <<= 1) {
        int tv = (t >= off) ? s[t - off] : 0;
        __syncthreads();
        s[t] += tv;
        __syncthreads();
    }
    int run = s[t] - sum;
#pragma unroll
    for (int i = 0; i < 8; ++i) { int v = loc[i]; tsum[t * 8 + i] = run; run += v; }
}

__global__ void scan_add_kernel(int* __restrict__ rp, const int* __restrict__ tsum) {
    int g = blockIdx.x * 256 + threadIdx.x;
    rp[g] += tsum[g >> 8];
}

__global__ void scatter_kernel(const int* __restrict__ src, const int* __restrict__ dst,
                               const int* __restrict__ etype, const float* __restrict__ norm,
                               int* __restrict__ rp, int2* __restrict__ erec) {
    int e = blockIdx.x * blockDim.x + threadIdx.x;
    if (e >= N_EDGES) return;
    int key = etype[e] * N_NODES + dst[e];
    int pos = atomicAdd(rp + key, 1);
    erec[pos] = make_int2(src[e], __float_as_int(norm[e]));
}

// ===========================================================================
// Weight pre-transpose to bf16 [outcol][k] layout.
// ===========================================================================
__global__ void wtrans_kernel(const float* __restrict__ W_t, const float* __restrict__ W_r,
                              unsigned short* __restrict__ WTp, unsigned short* __restrict__ WTl) {
    int u = blockIdx.x * 256 + threadIdx.x;
    if (u < 2560) {                       // proj: 128 cols x 20 kgroups
        int c = u / 20, k0 = (u % 20) * 8;
#pragma unroll
        for (int j = 0; j < 8; ++j) {
            int k = k0 + j;
            float v = (k < 133) ? W_t[k * HID + c] : 0.f;
            WTp[c * KPROJ + k] = f2bf(v);
        }
    } else if (u < 2560 + 16384) {        // layers: 2 x 128 cols x 64 kgroups
        int v = u - 2560;
        int l = v / 8192; int rr = v % 8192;
        int c = rr / 64; int k0 = (rr % 64) * 8;
#pragma unroll
        for (int j = 0; j < 8; ++j) {
            int k = k0 + j; int t = k >> 7; int i = k & 127;
            float w = W_r[(((size_t)(l * 4 + t) * HID) + i) * HID + c];
            WTl[((size_t)l * HID + c) * KLAY + k] = f2bf(w);
        }
    }
}

// ===========================================================================
// prep: build A0[N][160] bf16 = concat(emb', feats, zeros).  wave per node;
// 2 groups x 32 lanes x float4 -> 2 edges gathered concurrently.
// ===========================================================================
__global__ __launch_bounds__(256) void prep_kernel(
        const int* __restrict__ rp, const int2* __restrict__ erec,
        const int* __restrict__ gid,
        const int* __restrict__ spo, const int* __restrict__ access,
        const int* __restrict__ pre, const float* __restrict__ emb,
        unsigned short* __restrict__ A0) {
    int wave = threadIdx.x >> 6, lane = threadIdx.x & 63;
    int n = blockIdx.x * 4 + wave;
    int g = lane >> 5, sl = lane & 31;
    int s0 = spo[n * 3], s1 = spo[n * 3 + 1], s2 = spo[n * 3 + 2];
    int rb = n ? rp[n - 1] : 0, re = rp[n];
    float a0 = 0.f, a1 = 0.f, a2 = 0.f, a3 = 0.f;
    if ((s0 + s2) > 0 && re > rb) {
        for (int i = rb + g; i < re; i += 2) {
            int2 er = erec[i];
            float nm = __int_as_float(er.y);
            float4 v = ((const float4*)(emb + (size_t)gid[er.x] * HID))[sl];
            a0 += v.x * nm; a1 += v.y * nm; a2 += v.z * nm; a3 += v.w * nm;
        }
        a0 += __shfl_xor(a0, 32, 64);
        a1 += __shfl_xor(a1, 32, 64);
        a2 += __shfl_xor(a2, 32, 64);
        a3 += __shfl_xor(a3, 32, 64);
    } else if (g == 0) {
        float4 v = ((const float4*)(emb + (size_t)gid[n] * HID))[sl];
        a0 = v.x; a1 = v.y; a2 = v.z; a3 = v.w;
    }
    unsigned int* row = (unsigned int*)(A0 + (size_t)n * KPROJ);
    if (g == 0) {
        uint2 o; o.x = pack2(a0, a1); o.y = pack2(a2, a3);
        *(uint2*)(row + sl * 2) = o;
    }
    if (lane < 16) {
        int c0 = 128 + lane * 2;
        float f0 = 0.f, f1 = 0.f;
        if (c0 == 128)      { f0 = (float)s0;      f1 = (float)s1; }
        else if (c0 == 130) { f0 = (float)s2;      f1 = (float)access[n]; }
        else if (c0 == 132) { f0 = (float)pre[n];  f1 = 0.f; }
        row[64 + lane] = pack2(f0, f1);
    }
}

// ===========================================================================
// aggregation: wave per dst; 4 groups of 16 lanes, one per edge type.
// ===========================================================================
__device__ __forceinline__ void acc8(float* a, u32x4 v, float nm) {
    a[0] = fmaf(bf2f((unsigned short)(v.x & 0xffffu)), nm, a[0]);
    a[1] = fmaf(bf2f((unsigned short)(v.x >> 16)),     nm, a[1]);
    a[2] = fmaf(bf2f((unsigned short)(v.y & 0xffffu)), nm, a[2]);
    a[3] = fmaf(bf2f((unsigned short)(v.y >> 16)),     nm, a[3]);
    a[4] = fmaf(bf2f((unsigned short)(v.z & 0xffffu)), nm, a[4]);
    a[5] = fmaf(bf2f((unsigned short)(v.z >> 16)),     nm, a[5]);
    a[6] = fmaf(bf2f((unsigned short)(v.w & 0xffffu)), nm, a[6]);
    a[7] = fmaf(bf2f((unsigned short)(v.w >> 16)),     nm, a[7]);
}

__global__ __launch_bounds__(256) void agg_kernel(
        const int* __restrict__ rp, const int2* __restrict__ erec,
        const unsigned short* __restrict__ hb, unsigned short* __restrict__ Aagg) {
    int wave = threadIdx.x >> 6, lane = threadIdx.x & 63;
    int d = blockIdx.x * 4 + wave;
    int t = lane >> 4, sl = lane & 15;
    int key = t * N_NODES + d;
    int rb = key ? rp[key - 1] : 0;
    int re = rp[key];
    float a[8] = {0.f, 0.f, 0.f, 0.f, 0.f, 0.f, 0.f, 0.f};
    int i = rb;
    for (; i + 2 <= re; i += 2) {
        int2 e0 = erec[i];
        int2 e1 = erec[i + 1];
        u32x4 v0 = *((const u32x4*)(hb + (size_t)e0.x * HID) + sl);
        u32x4 v1 = *((const u32x4*)(hb + (size_t)e1.x * HID) + sl);
        acc8(a, v0, __int_as_float(e0.y));
        acc8(a, v1, __int_as_float(e1.y));
    }
    if (i < re) {
        int2 e0 = erec[i];
        u32x4 v0 = *((const u32x4*)(hb + (size_t)e0.x * HID) + sl);
        acc8(a, v0, __int_as_float(e0.y));
    }
    u32x4 o;
    o.x = pack2(a[0], a[1]); o.y = pack2(a[2], a[3]);
    o.z = pack2(a[4], a[5]); o.w = pack2(a[6], a[7]);
    __builtin_nontemporal_store(o, (u32x4*)(Aagg + (size_t)d * KLAY + t * HID) + sl);
}

// ===========================================================================
// MFMA GEMM, BK=64 chunks, global_load_lds staging with XOR-swizzle:
// LDS dest stays LINEAR (HW requirement); the global SOURCE chunk index and
// the ds_read chunk index are both XORed with (row & swz) -- same involution
// on both sides (guide rule 21).  16B chunk granularity.
// mode 0: out = acc+b; 1: relu(acc+b)+hb (residual); 2: relu(acc+b)
// ===========================================================================
__device__ __forceinline__ void stage_tile(const unsigned short* gbase, int ldK,
                                           int k0, int bk, unsigned short* lds,
                                           int wid, int lane) {
    int iters = bk >> 4;                  // 4 KiB (4 waves) per iter
    int sh = (bk == 64) ? 3 : 2;          // log2(16B-chunks per row)
    int msk = (1 << sh) - 1;
    int swz = (bk == 64) ? 7 : 3;
    for (int i = 0; i < iters; ++i) {
        int c = (i * 4 + wid) * 64 + lane;        // linear chunk index in tile
        int row = c >> sh, cc = c & msk;
        int ccg = cc ^ (row & swz);               // pre-swizzled source chunk
        const unsigned short* g = gbase + (size_t)row * ldK + k0 + ccg * 8;
        unsigned short* l = lds + (size_t)(i * 4 + wid) * 512;
        __builtin_amdgcn_global_load_lds(
            (const __attribute__((address_space(1))) void*)g,
            (__attribute__((address_space(3))) void*)l, 16, 0, 0);
    }
}

__global__ __launch_bounds__(256) void gemm_kernel(
        const unsigned short* __restrict__ A, int K,
        const unsigned short* __restrict__ WT, const float* __restrict__ bias,
        unsigned short* __restrict__ hb, int mode) {
    __shared__ unsigned short At[128 * 64];
    __shared__ unsigned short Bt[128 * 64];
    int tid = threadIdx.x;
    int base = blockIdx.x * 128;
    int wid = tid >> 6, lane = tid & 63;
    int wr = wid >> 1, wc = wid & 1;
    int lr = lane & 15, g16 = lane >> 4;
    f32x4 acc[4][4];
#pragma unroll
    for (int m = 0; m < 4; ++m)
#pragma unroll
        for (int n = 0; n < 4; ++n) { acc[m][n][0] = 0.f; acc[m][n][1] = 0.f; acc[m][n][2] = 0.f; acc[m][n][3] = 0.f; }
    const unsigned short* Abase = A + (size_t)base * K;
    for (int k0 = 0; k0 < K; k0 += 64) {
        int bk = K - k0; if (bk > 64) bk = 64;
        int swz = (bk == 64) ? 7 : 3;
        __syncthreads();
        stage_tile(Abase, K, k0, bk, At, wid, lane);
        stage_tile(WT,    K, k0, bk, Bt, wid, lane);
        __syncthreads();                 // drains vmcnt(0), data in LDS
        int ks = bk >> 5;
        for (int kk = 0; kk < ks; ++kk) {
            bf16x8 a[4], b[4];
            int cc = kk * 4 + g16;       // 16B chunk within row
#pragma unroll
            for (int m = 0; m < 4; ++m) {
                int ar = wr * 64 + m * 16 + lr;
                a[m] = *(const bf16x8*)&At[ar * bk + ((cc ^ (ar & swz)) << 3)];
            }
#pragma unroll
            for (int n = 0; n < 4; ++n) {
                int br = wc * 64 + n * 16 + lr;
                b[n] = *(const bf16x8*)&Bt[br * bk + ((cc ^ (br & swz)) << 3)];
            }
#pragma unroll
            for (int m = 0; m < 4; ++m)
#pragma unroll
                for (int n = 0; n < 4; ++n)
                    acc[m][n] = __builtin_amdgcn_mfma_f32_16x16x32_bf16(a[m], b[n], acc[m][n], 0, 0, 0);
        }
    }
    float bcol[4];
#pragma unroll
    for (int n = 0; n < 4; ++n) bcol[n] = bias[wc * 64 + n * 16 + lr];
    int r0g = (lane >> 4) * 4;
#pragma unroll
    for (int m = 0; m < 4; ++m) {
        int row = base + wr * 64 + m * 16 + r0g;
#pragma unroll
        for (int n = 0; n < 4; ++n) {
            int col = wc * 64 + n * 16 + lr;
#pragma unroll
            for (int r = 0; r < 4; ++r) {
                float v = acc[m][n][r] + bcol[n];
                size_t idx = (size_t)(row + r) * HID + col;
                if (mode == 1)      v = fmaxf(v, 0.f) + bf2f(hb[idx]);
                else if (mode == 2) v = fmaxf(v, 0.f);
                hb[idx] = f2bf(v);
            }
        }
    }
}

// ===========================================================================
// predict (h in bf16)
// ===========================================================================
__global__ void predict_kernel(const unsigned short* __restrict__ hb,
                               const int* __restrict__ pred_idx,
                               const float* __restrict__ Wb, const float* __restrict__ bbp,
                               float* __restrict__ out) {
    int b = blockIdx.x;
    int tid = threadIdx.x;
    __shared__ float hp[PPG * HID];
    __shared__ float pool[HID];
    __shared__ float vv[HID];
    __shared__ float sc[PPG];
    __shared__ float lse;
    for (int k = tid; k < PPG * HID; k += 256) {
        int p = k >> 7, j = k & 127;
        int node = pred_idx[b * PPG + p];
        hp[k] = bf2f(hb[(size_t)node * HID + j]);
    }
    __syncthreads();
    if (tid < HID) {
        float s = 0.f;
        for (int p = 0; p < PPG; ++p) s += hp[p * HID + tid];
        pool[tid] = s * (1.0f / PPG);
    }
    __syncthreads();
    if (tid < HID) {
        float s = 0.f;
        for (int k = 0; k < HID; ++k) s += Wb[tid * HID + k] * pool[k];
        vv[tid] = s;
    }
    __syncthreads();
    if (tid < PPG) {
        float s = bbp[0];
        for (int j = 0; j < HID; ++j) s += hp[tid * HID + j] * vv[j];
        sc[tid] = s;
    }
    __syncthreads();
    if (tid == 0) {
        float m = -INFINITY;
        for (int p = 0; p < PPG; ++p) m = fmaxf(m, sc[p]);
        float se = 0.f;
        for (int p = 0; p < PPG; ++p) se += expf(sc[p] - m);
        lse = m + logf(se);
    }
    __syncthreads();
    if (tid < PPG) out[b * PPG + tid] = sc[tid] - lse;
}

extern "C" void kernel_launch(void* const* d_in, const int* in_sizes, int n_in,
                              void* d_out, int out_size, void* d_ws, size_t ws_size,
                              hipStream_t stream) {
    const float* emb_table  = (const float*)d_in[0];
    const float* W_t        = (const float*)d_in[1];
    const float* b_t        = (const float*)d_in[2];
    const float* W_r        = (const float*)d_in[3];
    const float* b_r        = (const float*)d_in[4];
    const float* Wb         = (const float*)d_in[5];
    const float* bb         = (const float*)d_in[6];
    const float* norm       = (const float*)d_in[7];
    const int*   global_id  = (const int*)d_in[8];
    const int*   spo        = (const int*)d_in[9];
    const int*   access     = (const int*)d_in[10];
    const int*   pre_access = (const int*)d_in[11];
    const int*   src        = (const int*)d_in[12];
    const int*   dst        = (const int*)d_in[13];
    const int*   etype      = (const int*)d_in[14];
    const int*   pred_idx   = (const int*)d_in[15];
    float* out = (float*)d_out;

    char* ws = (char*)d_ws;
    size_t off = 0;
    unsigned short* hb   = (unsigned short*)(ws + off); off += (size_t)N_NODES * HID * 2;      // 32 MiB
    unsigned short* Abuf = (unsigned short*)(ws + off); off += (size_t)N_NODES * KLAY * 2;     // 128 MiB (A0 aliases)
    int*   rp    = (int*)(ws + off);   off += (size_t)NKEYS * 4;
    int*   tsum  = (int*)(ws + off);   off += (size_t)NTILES * 4;
    int2*  erec  = (int2*)(ws + off);  off += (size_t)N_EDGES * 8;
    unsigned short* WTp = (unsigned short*)(ws + off); off += (size_t)HID * KPROJ * 2;
    unsigned short* WTl = (unsigned short*)(ws + off); off += (size_t)2 * HID * KLAY * 2;
    unsigned short* A0 = Abuf;   // [N][KPROJ], consumed before Aagg overwrites

    // ---- CSR build ----
    hipMemsetAsync(rp, 0, (size_t)NKEYS * 4, stream);
    count_kernel<<<N_EDGES / 256, 256, 0, stream>>>(dst, etype, rp);
    scan_tile_kernel<<<NTILES, 256, 0, stream>>>(rp, tsum);
    scan_tsum_kernel<<<1, 256, 0, stream>>>(tsum);
    scan_add_kernel<<<NTILES, 256, 0, stream>>>(rp, tsum);
    scatter_kernel<<<N_EDGES / 256, 256, 0, stream>>>(src, dst, etype, norm, rp, erec);

    // ---- weights to bf16 transposed ----
    wtrans_kernel<<<74, 256, 0, stream>>>(W_t, W_r, WTp, WTl);

    // ---- init aggregation + A0 build, then proj GEMM -> hb ----
    prep_kernel<<<N_NODES / 4, 256, 0, stream>>>(rp, erec, global_id, spo,
                                                 access, pre_access, emb_table, A0);
    gemm_kernel<<<N_NODES / 128, 256, 0, stream>>>(A0, KPROJ, WTp, b_t, hb, 0);

    // ---- RGCN layers: aggregate-then-transform ----
    agg_kernel<<<N_NODES / 4, 256, 0, stream>>>(rp, erec, hb, Abuf);
    gemm_kernel<<<N_NODES / 128, 256, 0, stream>>>(Abuf, KLAY, WTl, b_r, hb, 1);
    agg_kernel<<<N_NODES / 4, 256, 0, stream>>>(rp, erec, hb, Abuf);
    gemm_kernel<<<N_NODES / 128, 256, 0, stream>>>(Abuf, KLAY, WTl + (size_t)HID * KLAY,
                                                   b_r + HID, hb, 2);

    predict_kernel<<<NB, 256, 0, stream>>>(hb, pred_idx, Wb, bb, out);
}

// Round 9
// 509.655 us; speedup vs baseline: 1.7227x; 1.0510x over previous
//
#include <hip/hip_runtime.h>
#include <hip/hip_bf16.h>

#define N_NODES 131072          // 2^17
#define N_EDGES 1048576
#define HID 128
#define NB 512
#define PPG 32
#define NTILES_D (N_NODES / 256)   // 512 scan tiles
#define KPROJ 160               // 133 real K, zero-padded (chunks 64+64+32)
#define KLAY  512               // 4 types x 128 (weight layout only)

typedef short bf16x8 __attribute__((ext_vector_type(8)));
typedef float f32x4  __attribute__((ext_vector_type(4)));
typedef unsigned int u32x4 __attribute__((ext_vector_type(4)));

__device__ __forceinline__ float bf2f(unsigned short u) {
    return __uint_as_float(((unsigned int)u) << 16);
}
__device__ __forceinline__ unsigned short f2bf(float x) {
    unsigned int u = __float_as_uint(x);
    unsigned int r = ((u >> 16) & 1u) + 0x7fffu;   // RNE
    return (unsigned short)((u + r) >> 16);
}
__device__ __forceinline__ unsigned int pack2(float a, float b) {
    return (unsigned int)f2bf(a) | ((unsigned int)f2bf(b) << 16);
}

// ===========================================================================
// CSR build over dst only (N keys); edge payload int2{src | type<<17, norm}
// ===========================================================================
__global__ void count_kernel(const int* __restrict__ dst, int* __restrict__ rp) {
    int e = blockIdx.x * blockDim.x + threadIdx.x;
    if (e >= N_EDGES) return;
    atomicAdd(rp + dst[e], 1);
}

__global__ void scan_tile_kernel(int* __restrict__ rp, int* __restrict__ tsum) {
    __shared__ int s[256];
    int g = blockIdx.x * 256 + threadIdx.x;
    int v = rp[g];
    s[threadIdx.x] = v;
    __syncthreads();
    for (int off = 1; off < 256; off <<= 1) {
        int tv = (threadIdx.x >= off) ? s[threadIdx.x - off] : 0;
        __syncthreads();
        s[threadIdx.x] += tv;
        __syncthreads();
    }
    rp[g] = s[threadIdx.x] - v;
    if (threadIdx.x == 255) tsum[blockIdx.x] = s[255];
}

__global__ void scan_tsum_kernel(int* __restrict__ tsum) {   // NTILES_D = 512
    __shared__ int s[256];
    int t = threadIdx.x;
    int loc[2]; int sum = 0;
#pragma unroll
    for (int i = 0; i < 2; ++i) { loc[i] = tsum[t * 2 + i]; sum += loc[i]; }
    s[t] = sum;
    __syncthreads();
    for (int off = 1; off < 256; off <<= 1) {
        int tv = (t >= off) ? s[t - off] : 0;
        __syncthreads();
        s[t] += tv;
        __syncthreads();
    }
    int run = s[t] - sum;
#pragma unroll
    for (int i = 0; i < 2; ++i) { int v = loc[i]; tsum[t * 2 + i] = run; run += v; }
}

__global__ void scan_add_kernel(int* __restrict__ rp, const int* __restrict__ tsum) {
    int g = blockIdx.x * 256 + threadIdx.x;
    rp[g] += tsum[g >> 8];
}

__global__ void scatter_kernel(const int* __restrict__ src, const int* __restrict__ dst,
                               const int* __restrict__ etype, const float* __restrict__ norm,
                               int* __restrict__ rp, int2* __restrict__ erec) {
    int e = blockIdx.x * blockDim.x + threadIdx.x;
    if (e >= N_EDGES) return;
    int pos = atomicAdd(rp + dst[e], 1);
    erec[pos] = make_int2(src[e] | (etype[e] << 17), __float_as_int(norm[e]));
}

// ===========================================================================
// Weight pre-transpose to bf16 [outcol][k] layout.
// WTp[c][k<160]; WTl[l][c][t*128+i] = W_r[l][t][i][c]
// ===========================================================================
__global__ void wtrans_kernel(const float* __restrict__ W_t, const float* __restrict__ W_r,
                              unsigned short* __restrict__ WTp, unsigned short* __restrict__ WTl) {
    int u = blockIdx.x * 256 + threadIdx.x;
    if (u < 2560) {                       // proj: 128 cols x 20 kgroups
        int c = u / 20, k0 = (u % 20) * 8;
#pragma unroll
        for (int j = 0; j < 8; ++j) {
            int k = k0 + j;
            float v = (k < 133) ? W_t[k * HID + c] : 0.f;
            WTp[c * KPROJ + k] = f2bf(v);
        }
    } else if (u < 2560 + 16384) {        // layers: 2 x 128 cols x 64 kgroups
        int v = u - 2560;
        int l = v / 8192; int rr = v % 8192;
        int c = rr / 64; int k0 = (rr % 64) * 8;
#pragma unroll
        for (int j = 0; j < 8; ++j) {
            int k = k0 + j; int t = k >> 7; int i = k & 127;
            float w = W_r[(((size_t)(l * 4 + t) * HID) + i) * HID + c];
            WTl[((size_t)l * HID + c) * KLAY + k] = f2bf(w);
        }
    }
}

// ===========================================================================
// prep: A0[N][160] bf16 = concat(emb', feats, 0).  wave/node, 2 groups x 32
// lanes; edges are mixed-type (dst CSR) -> type==0 predicate (group-uniform).
// ===========================================================================
__global__ __launch_bounds__(256) void prep_kernel(
        const int* __restrict__ rp, const int2* __restrict__ erec,
        const int* __restrict__ gid,
        const int* __restrict__ spo, const int* __restrict__ access,
        const int* __restrict__ pre, const float* __restrict__ emb,
        unsigned short* __restrict__ A0) {
    int wave = threadIdx.x >> 6, lane = threadIdx.x & 63;
    int n = blockIdx.x * 4 + wave;
    int g = lane >> 5, sl = lane & 31;
    int s0 = spo[n * 3], s1 = spo[n * 3 + 1], s2 = spo[n * 3 + 2];
    float a0 = 0.f, a1 = 0.f, a2 = 0.f, a3 = 0.f;
    int cnt = 0;
    bool isne = (s0 + s2) > 0;
    if (isne) {
        int rb = n ? rp[n - 1] : 0, re = rp[n];
        for (int i = rb + g; i < re; i += 2) {
            int2 er = erec[i];
            if (((er.x >> 17) & 3) == 0) {
                int s = er.x & 0x1FFFF;
                float nm = __int_as_float(er.y);
                float4 v = ((const float4*)(emb + (size_t)gid[s] * HID))[sl];
                a0 += v.x * nm; a1 += v.y * nm; a2 += v.z * nm; a3 += v.w * nm;
                cnt++;
            }
        }
        a0 += __shfl_xor(a0, 32, 64);
        a1 += __shfl_xor(a1, 32, 64);
        a2 += __shfl_xor(a2, 32, 64);
        a3 += __shfl_xor(a3, 32, 64);
        cnt += __shfl_xor(cnt, 32, 64);
    }
    if (!isne || cnt == 0) {
        if (g == 0) {
            float4 v = ((const float4*)(emb + (size_t)gid[n] * HID))[sl];
            a0 = v.x; a1 = v.y; a2 = v.z; a3 = v.w;
        }
    }
    unsigned int* row = (unsigned int*)(A0 + (size_t)n * KPROJ);
    if (g == 0) {
        uint2 o; o.x = pack2(a0, a1); o.y = pack2(a2, a3);
        *(uint2*)(row + sl * 2) = o;
    }
    if (lane < 16) {
        int c0 = 128 + lane * 2;
        float f0 = 0.f, f1 = 0.f;
        if (c0 == 128)      { f0 = (float)s0;      f1 = (float)s1; }
        else if (c0 == 130) { f0 = (float)s2;      f1 = (float)access[n]; }
        else if (c0 == 132) { f0 = (float)pre[n];  f1 = 0.f; }
        row[64 + lane] = pack2(f0, f1);
    }
}

// ===========================================================================
// staging helper: global_load_lds, linear LDS dest, XOR-pre-swizzled source.
// bk in {128, 64, 32}; 16B chunk granularity; swz = chunks/row - 1.
// ===========================================================================
__device__ __forceinline__ void stage_tile(const unsigned short* gbase, int ldK,
                                           int k0, int bk, unsigned short* lds,
                                           int wid, int lane) {
    int iters = bk >> 4;
    int sh = (bk == 128) ? 4 : ((bk == 64) ? 3 : 2);
    int msk = (1 << sh) - 1;
    for (int i = 0; i < iters; ++i) {
        int c = (i * 4 + wid) * 64 + lane;        // linear chunk index in tile
        int row = c >> sh, cc = c & msk;
        int ccg = cc ^ (row & msk);               // pre-swizzled source chunk
        const unsigned short* g = gbase + (size_t)row * ldK + k0 + ccg * 8;
        unsigned short* l = lds + (size_t)(i * 4 + wid) * 512;
        __builtin_amdgcn_global_load_lds(
            (const __attribute__((address_space(1))) void*)g,
            (__attribute__((address_space(3))) void*)l, 16, 0, 0);
    }
}

// ===========================================================================
// proj MFMA GEMM (K=160, BK=64/32): hb = A0 @ WTp^T + b_t
// ===========================================================================
__global__ __launch_bounds__(256) void gemm_kernel(
        const unsigned short* __restrict__ A, int K,
        const unsigned short* __restrict__ WT, const float* __restrict__ bias,
        unsigned short* __restrict__ hb) {
    __shared__ unsigned short At[128 * 64];
    __shared__ unsigned short Bt[128 * 64];
    int tid = threadIdx.x;
    int base = blockIdx.x * 128;
    int wid = tid >> 6, lane = tid & 63;
    int wr = wid >> 1, wc = wid & 1;
    int lr = lane & 15, g16 = lane >> 4;
    f32x4 acc[4][4];
#pragma unroll
    for (int m = 0; m < 4; ++m)
#pragma unroll
        for (int n = 0; n < 4; ++n) { acc[m][n][0] = 0.f; acc[m][n][1] = 0.f; acc[m][n][2] = 0.f; acc[m][n][3] = 0.f; }
    const unsigned short* Abase = A + (size_t)base * K;
    for (int k0 = 0; k0 < K; k0 += 64) {
        int bk = K - k0; if (bk > 64) bk = 64;
        int swz = (bk == 64) ? 7 : 3;
        __syncthreads();
        stage_tile(Abase, K, k0, bk, At, wid, lane);
        stage_tile(WT,    K, k0, bk, Bt, wid, lane);
        __syncthreads();
        int ks = bk >> 5;
        for (int kk = 0; kk < ks; ++kk) {
            bf16x8 a[4], b[4];
            int cc = kk * 4 + g16;
#pragma unroll
            for (int m = 0; m < 4; ++m) {
                int ar = wr * 64 + m * 16 + lr;
                a[m] = *(const bf16x8*)&At[ar * bk + ((cc ^ (ar & swz)) << 3)];
            }
#pragma unroll
            for (int n = 0; n < 4; ++n) {
                int br = wc * 64 + n * 16 + lr;
                b[n] = *(const bf16x8*)&Bt[br * bk + ((cc ^ (br & swz)) << 3)];
            }
#pragma unroll
            for (int m = 0; m < 4; ++m)
#pragma unroll
                for (int n = 0; n < 4; ++n)
                    acc[m][n] = __builtin_amdgcn_mfma_f32_16x16x32_bf16(a[m], b[n], acc[m][n], 0, 0, 0);
        }
    }
    float bcol[4];
#pragma unroll
    for (int n = 0; n < 4; ++n) bcol[n] = bias[wc * 64 + n * 16 + lr];
    int r0g = (lane >> 4) * 4;
#pragma unroll
    for (int m = 0; m < 4; ++m) {
        int row = base + wr * 64 + m * 16 + r0g;
#pragma unroll
        for (int n = 0; n < 4; ++n) {
            int col = wc * 64 + n * 16 + lr;
#pragma unroll
            for (int r = 0; r < 4; ++r)
                hb[(size_t)(row + r) * HID + col] = f2bf(acc[m][n][r] + bcol[n]);
        }
    }
}

// ===========================================================================
// xt4: XT[t][N][128] = hb @ W_r[l][t]  for all 4 types, A-tile staged ONCE.
// K=128 single chunk; B re-staged per type (L2-hot).
// ===========================================================================
__global__ __launch_bounds__(256) void xt4_kernel(
        const unsigned short* __restrict__ hb,
        const unsigned short* __restrict__ WTlayer,   // [c][t*128+k], ld=512
        unsigned short* __restrict__ XT) {
    __shared__ unsigned short Ah[128 * 128];
    __shared__ unsigned short Bt[128 * 128];
    int tid = threadIdx.x;
    int base = blockIdx.x * 128;
    int wid = tid >> 6, lane = tid & 63;
    int wr = wid >> 1, wc = wid & 1;
    int lr = lane & 15, g16 = lane >> 4;
    int r0g = (lane >> 4) * 4;

    stage_tile(hb + (size_t)base * HID, HID, 0, 128, Ah, wid, lane);
    stage_tile(WTlayer, KLAY, 0, 128, Bt, wid, lane);   // type 0
    __syncthreads();

    for (int t = 0; t < 4; ++t) {
        f32x4 acc[4][4];
#pragma unroll
        for (int m = 0; m < 4; ++m)
#pragma unroll
            for (int n = 0; n < 4; ++n) { acc[m][n][0] = 0.f; acc[m][n][1] = 0.f; acc[m][n][2] = 0.f; acc[m][n][3] = 0.f; }
#pragma unroll
        for (int kk = 0; kk < 4; ++kk) {
            bf16x8 a[4], b[4];
            int cc = kk * 4 + g16;
#pragma unroll
            for (int m = 0; m < 4; ++m) {
                int ar = wr * 64 + m * 16 + lr;
                a[m] = *(const bf16x8*)&Ah[ar * 128 + ((cc ^ (ar & 15)) << 3)];
            }
#pragma unroll
            for (int n = 0; n < 4; ++n) {
                int br = wc * 64 + n * 16 + lr;
                b[n] = *(const bf16x8*)&Bt[br * 128 + ((cc ^ (br & 15)) << 3)];
            }
#pragma unroll
            for (int m = 0; m < 4; ++m)
#pragma unroll
                for (int n = 0; n < 4; ++n)
                    acc[m][n] = __builtin_amdgcn_mfma_f32_16x16x32_bf16(a[m], b[n], acc[m][n], 0, 0, 0);
        }
        unsigned short* XTt = XT + ((size_t)t << 17) * HID;
#pragma unroll
        for (int m = 0; m < 4; ++m) {
            int row = base + wr * 64 + m * 16 + r0g;
#pragma unroll
            for (int n = 0; n < 4; ++n) {
                int col = wc * 64 + n * 16 + lr;
#pragma unroll
                for (int r = 0; r < 4; ++r)
                    XTt[(size_t)(row + r) * HID + col] = f2bf(acc[m][n][r]);
            }
        }
        if (t < 3) {
            __syncthreads();   // all waves done reading Bt
            stage_tile(WTlayer, KLAY, (t + 1) * HID, 128, Bt, wid, lane);
            __syncthreads();   // drain
        }
    }
}

// ===========================================================================
// fused aggregation: wave per dst over mixed-type segment; 4 groups x 16
// lanes process edges round-robin, gathering from XT[type]; 2-round shfl
// tree reduce; epilogue bias+relu(+residual) written IN PLACE on hb.
// ===========================================================================
__device__ __forceinline__ void acc8(float* a, u32x4 v, float nm) {
    a[0] = fmaf(bf2f((unsigned short)(v.x & 0xffffu)), nm, a[0]);
    a[1] = fmaf(bf2f((unsigned short)(v.x >> 16)),     nm, a[1]);
    a[2] = fmaf(bf2f((unsigned short)(v.y & 0xffffu)), nm, a[2]);
    a[3] = fmaf(bf2f((unsigned short)(v.y >> 16)),     nm, a[3]);
    a[4] = fmaf(bf2f((unsigned short)(v.z & 0xffffu)), nm, a[4]);
    a[5] = fmaf(bf2f((unsigned short)(v.z >> 16)),     nm, a[5]);
    a[6] = fmaf(bf2f((unsigned short)(v.w & 0xffffu)), nm, a[6]);
    a[7] = fmaf(bf2f((unsigned short)(v.w >> 16)),     nm, a[7]);
}

__global__ __launch_bounds__(256) void agg_kernel(
        const int* __restrict__ rp, const int2* __restrict__ erec,
        const unsigned short* __restrict__ XT, const float* __restrict__ bias,
        unsigned short* __restrict__ hb, int residual) {
    int wave = threadIdx.x >> 6, lane = threadIdx.x & 63;
    int d = blockIdx.x * 4 + wave;
    int g = lane >> 4, sl = lane & 15;
    int rb = d ? rp[d - 1] : 0;
    int re = rp[d];
    float a[8] = {0.f, 0.f, 0.f, 0.f, 0.f, 0.f, 0.f, 0.f};
    for (int i = rb + g; i < re; i += 4) {
        int2 er = erec[i];
        int st = er.x;                      // src | type<<17
        float nm = __int_as_float(er.y);
        u32x4 v = *((const u32x4*)(XT + (size_t)(st & 0x7FFFF) * HID) + sl);
        acc8(a, v, nm);
    }
#pragma unroll
    for (int k = 0; k < 8; ++k) {
        a[k] += __shfl_xor(a[k], 16, 64);
        a[k] += __shfl_xor(a[k], 32, 64);
    }
    if (g == 0) {
        float r[8];
#pragma unroll
        for (int j = 0; j < 8; ++j) r[j] = fmaxf(a[j] + bias[sl * 8 + j], 0.f);
        unsigned short* hrow = hb + (size_t)d * HID;
        if (residual) {
            u32x4 hv = *((const u32x4*)hrow + sl);
            r[0] += bf2f((unsigned short)(hv.x & 0xffffu));
            r[1] += bf2f((unsigned short)(hv.x >> 16));
            r[2] += bf2f((unsigned short)(hv.y & 0xffffu));
            r[3] += bf2f((unsigned short)(hv.y >> 16));
            r[4] += bf2f((unsigned short)(hv.z & 0xffffu));
            r[5] += bf2f((unsigned short)(hv.z >> 16));
            r[6] += bf2f((unsigned short)(hv.w & 0xffffu));
            r[7] += bf2f((unsigned short)(hv.w >> 16));
        }
        u32x4 o;
        o.x = pack2(r[0], r[1]); o.y = pack2(r[2], r[3]);
        o.z = pack2(r[4], r[5]); o.w = pack2(r[6], r[7]);
        *((u32x4*)hrow + sl) = o;
    }
}

// ===========================================================================
// predict (h in bf16)
// ===========================================================================
__global__ void predict_kernel(const unsigned short* __restrict__ hb,
                               const int* __restrict__ pred_idx,
                               const float* __restrict__ Wb, const float* __restrict__ bbp,
                               float* __restrict__ out) {
    int b = blockIdx.x;
    int tid = threadIdx.x;
    __shared__ float hp[PPG * HID];
    __shared__ float pool[HID];
    __shared__ float vv[HID];
    __shared__ float sc[PPG];
    __shared__ float lse;
    for (int k = tid; k < PPG * HID; k += 256) {
        int p = k >> 7, j = k & 127;
        int node = pred_idx[b * PPG + p];
        hp[k] = bf2f(hb[(size_t)node * HID + j]);
    }
    __syncthreads();
    if (tid < HID) {
        float s = 0.f;
        for (int p = 0; p < PPG; ++p) s += hp[p * HID + tid];
        pool[tid] = s * (1.0f / PPG);
    }
    __syncthreads();
    if (tid < HID) {
        float s = 0.f;
        for (int k = 0; k < HID; ++k) s += Wb[tid * HID + k] * pool[k];
        vv[tid] = s;
    }
    __syncthreads();
    if (tid < PPG) {
        float s = bbp[0];
        for (int j = 0; j < HID; ++j) s += hp[tid * HID + j] * vv[j];
        sc[tid] = s;
    }
    __syncthreads();
    if (tid == 0) {
        float m = -INFINITY;
        for (int p = 0; p < PPG; ++p) m = fmaxf(m, sc[p]);
        float se = 0.f;
        for (int p = 0; p < PPG; ++p) se += expf(sc[p] - m);
        lse = m + logf(se);
    }
    __syncthreads();
    if (tid < PPG) out[b * PPG + tid] = sc[tid] - lse;
}

extern "C" void kernel_launch(void* const* d_in, const int* in_sizes, int n_in,
                              void* d_out, int out_size, void* d_ws, size_t ws_size,
                              hipStream_t stream) {
    const float* emb_table  = (const float*)d_in[0];
    const float* W_t        = (const float*)d_in[1];
    const float* b_t        = (const float*)d_in[2];
    const float* W_r        = (const float*)d_in[3];
    const float* b_r        = (const float*)d_in[4];
    const float* Wb         = (const float*)d_in[5];
    const float* bb         = (const float*)d_in[6];
    const float* norm       = (const float*)d_in[7];
    const int*   global_id  = (const int*)d_in[8];
    const int*   spo        = (const int*)d_in[9];
    const int*   access     = (const int*)d_in[10];
    const int*   pre_access = (const int*)d_in[11];
    const int*   src        = (const int*)d_in[12];
    const int*   dst        = (const int*)d_in[13];
    const int*   etype      = (const int*)d_in[14];
    const int*   pred_idx   = (const int*)d_in[15];
    float* out = (float*)d_out;

    char* ws = (char*)d_ws;
    size_t off = 0;
    unsigned short* hb  = (unsigned short*)(ws + off); off += (size_t)N_NODES * HID * 2;       // 32 MiB
    unsigned short* XT  = (unsigned short*)(ws + off); off += (size_t)4 * N_NODES * HID * 2;   // 128 MiB (A0 aliases)
    int*   rp    = (int*)(ws + off);   off += (size_t)N_NODES * 4;                              // 512 KiB
    int*   tsum  = (int*)(ws + off);   off += (size_t)NTILES_D * 4;
    int2*  erec  = (int2*)(ws + off);  off += (size_t)N_EDGES * 8;                              // 8 MiB
    unsigned short* WTp = (unsigned short*)(ws + off); off += (size_t)HID * KPROJ * 2;
    unsigned short* WTl = (unsigned short*)(ws + off); off += (size_t)2 * HID * KLAY * 2;
    unsigned short* A0 = XT;   // [N][KPROJ], consumed by proj before XT written

    // ---- CSR build (dst-only keys) ----
    hipMemsetAsync(rp, 0, (size_t)N_NODES * 4, stream);
    count_kernel<<<N_EDGES / 256, 256, 0, stream>>>(dst, rp);
    scan_tile_kernel<<<NTILES_D, 256, 0, stream>>>(rp, tsum);
    scan_tsum_kernel<<<1, 256, 0, stream>>>(tsum);
    scan_add_kernel<<<NTILES_D, 256, 0, stream>>>(rp, tsum);
    scatter_kernel<<<N_EDGES / 256, 256, 0, stream>>>(src, dst, etype, norm, rp, erec);

    // ---- weights to bf16 transposed ----
    wtrans_kernel<<<74, 256, 0, stream>>>(W_t, W_r, WTp, WTl);

    // ---- init aggregation + A0 build, then proj GEMM -> hb ----
    prep_kernel<<<N_NODES / 4, 256, 0, stream>>>(rp, erec, global_id, spo,
                                                 access, pre_access, emb_table, A0);
    gemm_kernel<<<N_NODES / 128, 256, 0, stream>>>(A0, KPROJ, WTp, b_t, hb);

    // ---- RGCN layers: transform-first (xt4) + fused in-place aggregation ----
    xt4_kernel<<<N_NODES / 128, 256, 0, stream>>>(hb, WTl, XT);
    agg_kernel<<<N_NODES / 4, 256, 0, stream>>>(rp, erec, XT, b_r, hb, 1);
    xt4_kernel<<<N_NODES / 128, 256, 0, stream>>>(hb, WTl + (size_t)HID * KLAY, XT);
    agg_kernel<<<N_NODES / 4, 256, 0, stream>>>(rp, erec, XT, b_r + HID, hb, 0);

    predict_kernel<<<NB, 256, 0, stream>>>(hb, pred_idx, Wb, bb, out);
}